// Round 9
// baseline (5727.316 us; speedup 1.0000x reference)
//
#include <hip/hip_runtime.h>
#include <hip/hip_bf16.h>

#define VOCAB 100
#define EDIM  128
#define HDIM  256
#define LDIM  64
#define G3    768
#define TT    128
#define BB    4096
#define LROW  (TT * VOCAB)
#define H_LD  264            // halfs per h-row (256 + 8 pad)
#define ROWS  8              // batch rows per RNN block (2 blocks/CU)

typedef float    f32x4 __attribute__((ext_vector_type(4)));
typedef _Float16 f16x8 __attribute__((ext_vector_type(8)));
typedef _Float16 f16x4 __attribute__((ext_vector_type(4)));

__device__ __forceinline__ float sigf(float x) {
    return __builtin_amdgcn_rcpf(1.0f + __expf(-x));
}
__device__ __forceinline__ float tanh_f(float x) {
    return 2.0f * __builtin_amdgcn_rcpf(1.0f + __expf(-2.0f * x)) - 1.0f;
}
__device__ __forceinline__ void barrier_lgkm() {
    asm volatile("s_waitcnt lgkmcnt(0)\n\ts_barrier" ::: "memory");
}
__device__ __forceinline__ f16x8 ld_bfrag(const float* __restrict__ W, int outcol, int ks, int lgrp) {
    const float* p = W + outcol * HDIM + ks * 32 + lgrp * 8;
    float4 a = *(const float4*)p;
    float4 b = *(const float4*)(p + 4);
    f16x8 w = {(_Float16)a.x, (_Float16)a.y, (_Float16)a.z, (_Float16)a.w,
               (_Float16)b.x, (_Float16)b.y, (_Float16)b.z, (_Float16)b.w};
    return w;
}

// ---------------- prep: PT2[v][g] = enc_Wih@emb[v] + enc_bih + (g<512 ? enc_bhh : 0), f16 ----------------
__global__ void pt_kernel(const float* __restrict__ emb, const float* __restrict__ Wih,
                          const float* __restrict__ bih, const float* __restrict__ bhh,
                          _Float16* __restrict__ PT) {
    int v = blockIdx.x;
    __shared__ float se[EDIM];
    for (int e = threadIdx.x; e < EDIM; e += blockDim.x) se[e] = emb[v * EDIM + e];
    __syncthreads();
    for (int g = threadIdx.x; g < G3; g += blockDim.x) {
        const float* wr = Wih + g * EDIM;
        float acc = bih[g] + (g < 512 ? bhh[g] : 0.0f);
        #pragma unroll 8
        for (int e = 0; e < EDIM; ++e) acc += se[e] * wr[e];
        PT[v * G3 + g] = (_Float16)acc;
    }
}

// ===================================================================
// ENCODER: 8 rows/block, 512 blocks -> 2 blocks/CU (two interleaved
// convoys). Rows 8..15 of the h tile stay zero.
// ===================================================================
__global__ __launch_bounds__(1024, 8) void enc_kernel(
    const int* __restrict__ x, const _Float16* __restrict__ PT2,
    const float* __restrict__ Whh, const float* __restrict__ bhh,
    float* __restrict__ out)
{
    __shared__ _Float16 s_h[2][16 * H_LD];   // 16896 B
    __shared__ int s_tok[ROWS * TT];         // 4096 B

    const int tid  = threadIdx.x;
    const int lane = tid & 63;
    const int wv   = tid >> 6;
    const int l15  = lane & 15;
    const int lgrp = lane >> 4;
    const int bbase = blockIdx.x * ROWS;
    const int col  = wv * 16 + l15;

    for (int i = tid; i < ROWS * TT; i += 1024) s_tok[i] = x[bbase * TT + i];

    f16x8 Breg[3][8];
    #pragma unroll
    for (int g = 0; g < 3; ++g)
        #pragma unroll
        for (int ks = 0; ks < 8; ++ks)
            Breg[g][ks] = ld_bfrag(Whh, g * 256 + col, ks, lgrp);

    const float bhn = bhh[512 + col];
    float hst[4] = {0.f, 0.f, 0.f, 0.f};

    for (int i = tid; i < 2 * 16 * H_LD; i += 1024) ((_Float16*)s_h)[i] = (_Float16)0.f;
    __syncthreads();

    const f32x4 z4 = {0.f, 0.f, 0.f, 0.f};

    #pragma unroll 1
    for (int t = 0; t < TT; ++t) {
        const _Float16* rh = s_h[t & 1];
        _Float16* wh = s_h[(t + 1) & 1];

        f32x4 a0 = z4, a1 = z4, a2 = z4;
        #pragma unroll
        for (int ks = 0; ks < 8; ++ks) {
            f16x8 a = *(const f16x8*)(rh + l15 * H_LD + ks * 32 + lgrp * 8);
            a0 = __builtin_amdgcn_mfma_f32_16x16x32_f16(a, Breg[0][ks], a0, 0, 0, 0);
            a1 = __builtin_amdgcn_mfma_f32_16x16x32_f16(a, Breg[1][ks], a1, 0, 0, 0);
            a2 = __builtin_amdgcn_mfma_f32_16x16x32_f16(a, Breg[2][ks], a2, 0, 0, 0);
        }
        if (lgrp < 2) {
            #pragma unroll
            for (int j = 0; j < 4; ++j) {
                const int row = lgrp * 4 + j;              // 0..7
                const int tok = s_tok[row * TT + t];
                const _Float16* p = PT2 + tok * G3 + col;
                float xr = (float)p[0], xz = (float)p[256], xn = (float)p[512];
                float rg = sigf(a0[j] + xr);
                float zg = sigf(a1[j] + xz);
                float n  = tanh_f(xn + rg * (a2[j] + bhn));
                float h  = n + zg * (hst[j] - n);
                hst[j] = h;
                wh[row * H_LD + col] = (_Float16)h;
                if (t == TT - 1) out[(size_t)(bbase + row) * LROW + col] = h;
            }
        }
        barrier_lgkm();
    }
}

// ===================================================================
// DECODER RNN: 8 rows/block, 512 blocks -> 2 blocks/CU; streams h_t to
// Hbuf (4 KB coalesced per block-step).
// ===================================================================
__global__ __launch_bounds__(1024, 8) void dec_rnn_kernel(
    const float* __restrict__ eps,
    const float* __restrict__ mu_W, const float* __restrict__ mu_b,
    const float* __restrict__ lv_W, const float* __restrict__ lv_b,
    const float* __restrict__ di_W, const float* __restrict__ di_b,
    const float* __restrict__ dec_Wih, const float* __restrict__ dec_Whh,
    const float* __restrict__ dec_bih, const float* __restrict__ dec_bhh,
    float* __restrict__ out, _Float16* __restrict__ Hbuf)
{
    __shared__ _Float16 s_hb[2][16 * H_LD];   // 16896 B
    __shared__ f16x4 s_zp[256 * 9];           // 18432 B {r,z,n,_} per (col,row)
    __shared__ float s_hl[ROWS * 260];        // 8320 B

    const int tid  = threadIdx.x;
    const int lane = tid & 63;
    const int wv   = tid >> 6;
    const int l15  = lane & 15;
    const int lgrp = lane >> 4;
    const int bbase = blockIdx.x * ROWS;
    const int col  = wv * 16 + l15;

    for (int i = tid; i < 2 * 16 * H_LD; i += 1024) ((_Float16*)s_hb)[i] = (_Float16)0.f;
    for (int i = tid; i < ROWS * HDIM; i += 1024) {
        int m = i >> 8, c = i & 255;
        s_hl[m * 260 + c] = out[(size_t)(bbase + m) * LROW + c];
    }

    f16x8 Breg[3][8];
    #pragma unroll
    for (int g = 0; g < 3; ++g)
        #pragma unroll
        for (int ks = 0; ks < 8; ++ks)
            Breg[g][ks] = ld_bfrag(dec_Whh, g * 256 + col, ks, lgrp);
    __syncthreads();

    // ---- mu / logvar / z : 512 work items ----
    float zv = 0.0f;
    if (tid < 512) {
        const size_t MU_OFF = (size_t)BB * TT * VOCAB;
        const size_t LV_OFF = MU_OFF + (size_t)BB * LDIM;
        int m = tid >> 6, j = tid & 63;
        const float* mwr = mu_W + j * HDIM;
        const float* lwr = lv_W + j * HDIM;
        float am = mu_b[j], al = lv_b[j];
        #pragma unroll 4
        for (int k = 0; k < HDIM; ++k) { float hv = s_hl[m * 260 + k]; am += hv * mwr[k]; al += hv * lwr[k]; }
        size_t bo = (size_t)(bbase + m) * LDIM + j;
        out[MU_OFF + bo] = am;
        out[LV_OFF + bo] = al;
        zv = am + eps[bo] * __expf(0.5f * al);
    }
    __syncthreads();                 // h_last reads done
    if (tid < 512) s_hl[(tid >> 6) * 260 + (tid & 63)] = zv;
    __syncthreads();                 // z staged (rows 0..7, cols 0..63)

    // ---- hidden = tanh(di_W z + di_b); zp = dec_Wih z + dec_bih (+bhh r,z) ----
    {
        const int gc = tid & 255;
        const int gm2 = tid >> 8;    // 0..3, each 2 rows
        float ah[2], ar[2], az[2], an[2];
        float dib = di_b[gc];
        float bir = dec_bih[gc], biz = dec_bih[gc + 256], bin_ = dec_bih[gc + 512];
        #pragma unroll
        for (int i = 0; i < 2; ++i) { ah[i] = dib; ar[i] = bir; az[i] = biz; an[i] = bin_; }
        const float* w0 = di_W + gc * LDIM;
        const float* w1 = dec_Wih + gc * LDIM;
        const float* w2 = dec_Wih + (gc + 256) * LDIM;
        const float* w3 = dec_Wih + (gc + 512) * LDIM;
        #pragma unroll 2
        for (int j = 0; j < LDIM; ++j) {
            float a0 = w0[j], a1 = w1[j], a2 = w2[j], a3 = w3[j];
            #pragma unroll
            for (int i = 0; i < 2; ++i) {
                float q = s_hl[(gm2 * 2 + i) * 260 + j];
                ah[i] += q * a0; ar[i] += q * a1; az[i] += q * a2; an[i] += q * a3;
            }
        }
        float bhr = dec_bhh[gc], bhz = dec_bhh[gc + 256];
        __syncthreads();             // z reads done before s_hl overwrite
        #pragma unroll
        for (int i = 0; i < 2; ++i) {
            int r = gm2 * 2 + i;
            float th = tanh_f(ah[i]);
            s_hl[r * 260 + gc] = th;
            f16x4 q = {(_Float16)(ar[i] + bhr), (_Float16)(az[i] + bhz), (_Float16)an[i], (_Float16)0.f};
            s_zp[gc * 9 + r] = q;
            s_hb[0][r * H_LD + gc] = (_Float16)th;
        }
    }
    __syncthreads();                 // th/zp/h0 staged

    float hpr[4] = {0.f, 0.f, 0.f, 0.f};
    if (lgrp < 2) {
        #pragma unroll
        for (int j = 0; j < 4; ++j) hpr[j] = s_hl[(lgrp * 4 + j) * 260 + col];
    }

    const float bhn = dec_bhh[512 + col];
    const f32x4 z4 = {0.f, 0.f, 0.f, 0.f};
    const int crow = tid >> 6;       // copy-out row (tid<512 -> 0..7)
    const int cseg = tid & 63;

    #pragma unroll 1
    for (int t = 0; t < TT; ++t) {
        const _Float16* rh = s_hb[t & 1];
        _Float16* wh = s_hb[(t + 1) & 1];

        f32x4 a0 = z4, a1 = z4, a2 = z4;
        #pragma unroll
        for (int ks = 0; ks < 8; ++ks) {
            f16x8 a = *(const f16x8*)(rh + l15 * H_LD + ks * 32 + lgrp * 8);
            a0 = __builtin_amdgcn_mfma_f32_16x16x32_f16(a, Breg[0][ks], a0, 0, 0, 0);
            a1 = __builtin_amdgcn_mfma_f32_16x16x32_f16(a, Breg[1][ks], a1, 0, 0, 0);
            a2 = __builtin_amdgcn_mfma_f32_16x16x32_f16(a, Breg[2][ks], a2, 0, 0, 0);
        }
        if (lgrp < 2) {
            #pragma unroll
            for (int j = 0; j < 4; ++j) {
                const int row = lgrp * 4 + j;          // 0..7
                f16x4 q = s_zp[col * 9 + row];
                float rg = sigf(a0[j] + (float)q[0]);
                float zg = sigf(a1[j] + (float)q[1]);
                float n  = tanh_f((float)q[2] + rg * (a2[j] + bhn));
                float h  = n + zg * (hpr[j] - n);
                hpr[j] = h;
                wh[row * H_LD + col] = (_Float16)h;
            }
        }
        barrier_lgkm();
        if (tid < 512) {             // stream h_{t+1} (logits row s=t): 4 KB coalesced
            f16x4 hv = *(const f16x4*)(wh + crow * H_LD + cseg * 4);
            *(f16x4*)(Hbuf + (((size_t)(bbase + crow) * TT + t) * 256 + cseg * 4)) = hv;
        }
    }
}

// ===================================================================
// LOGITS GEMM with LDS-staged LINEAR copy-out (kills sector RMW):
// logits[M=BB*TT][100] = H[M][256] @ out_W^T + out_b
// 1024 blocks x 1024 thr; 2 rounds x (16 waves x 1 tile of 16 rows).
// ===================================================================
__global__ __launch_bounds__(1024, 4) void logits_kernel(
    const _Float16* __restrict__ Hbuf, const float* __restrict__ out_W,
    const float* __restrict__ out_b, float* __restrict__ out)
{
    __shared__ __attribute__((aligned(16))) unsigned char s_outw[VOCAB * 512]; // 51200 B
    __shared__ __attribute__((aligned(16))) float s_ls[256 * 108];             // 110592 B
    const int tid = threadIdx.x, lane = tid & 63, wv = tid >> 6;
    const int l15 = lane & 15, lgrp = lane >> 4;

    for (int idx = tid; idx < VOCAB * HDIM; idx += 1024) {
        int r = idx >> 8, k = idx & 255;
        _Float16 w = (_Float16)out_W[r * 256 + k];
        *(short*)(s_outw + r * 512 + ((2 * k) ^ ((r & 7) << 4))) = __builtin_bit_cast(short, w);
    }
    __syncthreads();

    float ob[7];
    #pragma unroll
    for (int vt = 0; vt < 7; ++vt) {
        int v = vt * 16 + l15;
        ob[vt] = (v < VOCAB) ? out_b[v] : 0.0f;
    }
    const f32x4 z4 = {0.f, 0.f, 0.f, 0.f};

    #pragma unroll 1
    for (int round = 0; round < 2; ++round) {
        size_t mt = (size_t)blockIdx.x * 32 + round * 16 + wv;   // 16-row tile index
        const _Float16* hrow = Hbuf + (mt * 16 + l15) * 256;
        f32x4 acc[7];
        #pragma unroll
        for (int vt = 0; vt < 7; ++vt) acc[vt] = z4;
        #pragma unroll
        for (int ks = 0; ks < 8; ++ks) {
            f16x8 a = *(const f16x8*)(hrow + ks * 32 + lgrp * 8);
            #pragma unroll
            for (int vt = 0; vt < 7; ++vt) {
                int orow = vt * 16 + l15; if (orow > VOCAB - 1) orow = VOCAB - 1;
                f16x8 wo = *(const f16x8*)(s_outw + orow * 512 + ((ks * 64 + lgrp * 16) ^ ((orow & 7) << 4)));
                acc[vt] = __builtin_amdgcn_mfma_f32_16x16x32_f16(a, wo, acc[vt], 0, 0, 0);
            }
        }
        // stage wave tile -> s_ls[local 256 rows][108]
        #pragma unroll
        for (int vt = 0; vt < 7; ++vt) {
            int v = vt * 16 + l15;
            if (v < VOCAB) {
                #pragma unroll
                for (int j = 0; j < 4; ++j)
                    s_ls[(wv * 16 + lgrp * 4 + j) * 108 + v] = acc[vt][j] + ob[vt];
            }
        }
        __syncthreads();
        // linear copy-out: 256 rows x 100 f32 = 6400 f32x4 chunks, contiguous
        {
            size_t slabM0 = (size_t)blockIdx.x * 512 + round * 256;
            float* gbase = out + slabM0 * VOCAB;
            for (int c = tid; c < 6400; c += 1024) {
                int r = c / 25, cc = (c % 25) * 4;
                f32x4 vch = *(const f32x4*)(s_ls + r * 108 + cc);
                *(f32x4*)(gbase + (size_t)c * 4) = vch;
            }
        }
        __syncthreads();
    }
}

// ===================================================================
// FALLBACK fused decoder (R6, known-passing, 16 rows/block) — ws too small.
// ===================================================================
#define ZP_LD 17
__global__ __launch_bounds__(1024, 4) void dec_fused_kernel(
    const float* __restrict__ eps,
    const float* __restrict__ mu_W, const float* __restrict__ mu_b,
    const float* __restrict__ lv_W, const float* __restrict__ lv_b,
    const float* __restrict__ di_W, const float* __restrict__ di_b,
    const float* __restrict__ dec_Wih, const float* __restrict__ dec_Whh,
    const float* __restrict__ dec_bih, const float* __restrict__ dec_bhh,
    const float* __restrict__ out_W, const float* __restrict__ out_b,
    float* __restrict__ out)
{
    __shared__ _Float16 s_hb[2][16 * H_LD];
    __shared__ f16x4 s_zp[256 * ZP_LD];
    __shared__ __attribute__((aligned(16))) unsigned char s_outw[VOCAB * 512];
    __shared__ float s_hl[16 * 260];

    const int tid  = threadIdx.x;
    const int lane = tid & 63;
    const int wv   = tid >> 6;
    const int l15  = lane & 15;
    const int lgrp = lane >> 4;
    const int bbase = blockIdx.x * 16;
    const int col  = wv * 16 + l15;

    for (int i = tid; i < 16 * HDIM; i += 1024) {
        int m = i >> 8, c = i & 255;
        s_hl[m * 260 + c] = out[(size_t)(bbase + m) * LROW + c];
    }
    for (int idx = tid; idx < VOCAB * HDIM; idx += 1024) {
        int r = idx >> 8, k = idx & 255;
        _Float16 w = (_Float16)out_W[r * 256 + k];
        *(short*)(s_outw + r * 512 + ((2 * k) ^ ((r & 7) << 4))) = __builtin_bit_cast(short, w);
    }

    f16x8 Breg[3][8];
    #pragma unroll
    for (int g = 0; g < 3; ++g)
        #pragma unroll
        for (int ks = 0; ks < 8; ++ks)
            Breg[g][ks] = ld_bfrag(dec_Whh, g * 256 + col, ks, lgrp);
    __syncthreads();

    float zv;
    {
        const size_t MU_OFF = (size_t)BB * TT * VOCAB;
        const size_t LV_OFF = MU_OFF + (size_t)BB * LDIM;
        int m = tid >> 6, j = tid & 63;
        const float* mwr = mu_W + j * HDIM;
        const float* lwr = lv_W + j * HDIM;
        float am = mu_b[j], al = lv_b[j];
        #pragma unroll 4
        for (int k = 0; k < HDIM; ++k) { float hv = s_hl[m * 260 + k]; am += hv * mwr[k]; al += hv * lwr[k]; }
        size_t bo = (size_t)(bbase + m) * LDIM + j;
        out[MU_OFF + bo] = am;
        out[LV_OFF + bo] = al;
        zv = am + eps[bo] * __expf(0.5f * al);
    }
    __syncthreads();
    { int m = tid >> 6, j = tid & 63; s_hl[m * 260 + j] = zv; }
    __syncthreads();

    float th[4];
    {
        const int gc = tid & 255;
        const int gm = tid >> 8;
        float ah[4], ar[4], az[4], an[4];
        float dib = di_b[gc];
        float bir = dec_bih[gc], biz = dec_bih[gc + 256], bin_ = dec_bih[gc + 512];
        #pragma unroll
        for (int i = 0; i < 4; ++i) { ah[i] = dib; ar[i] = bir; az[i] = biz; an[i] = bin_; }
        const float* w0 = di_W + gc * LDIM;
        const float* w1 = dec_Wih + gc * LDIM;
        const float* w2 = dec_Wih + (gc + 256) * LDIM;
        const float* w3 = dec_Wih + (gc + 512) * LDIM;
        #pragma unroll 2
        for (int j = 0; j < LDIM; ++j) {
            float a0 = w0[j], a1 = w1[j], a2 = w2[j], a3 = w3[j];
            #pragma unroll
            for (int i = 0; i < 4; ++i) {
                float q = s_hl[(gm * 4 + i) * 260 + j];
                ah[i] += q * a0; ar[i] += q * a1; az[i] += q * a2; an[i] += q * a3;
            }
        }
        float bhr = dec_bhh[gc], bhz = dec_bhh[gc + 256];
        __syncthreads();
        #pragma unroll
        for (int i = 0; i < 4; ++i) {
            int r = gm * 4 + i;
            th[i] = tanh_f(ah[i]);
            s_hl[r * 260 + gc] = th[i];
            f16x4 q = {(_Float16)(ar[i] + bhr), (_Float16)(az[i] + bhz), (_Float16)an[i], (_Float16)0.f};
            s_zp[gc * ZP_LD + r] = q;
            s_hb[0][r * H_LD + gc] = (_Float16)th[i];
        }
    }
    __syncthreads();

    float hpr[4];
    #pragma unroll
    for (int j = 0; j < 4; ++j) hpr[j] = s_hl[(lgrp * 4 + j) * 260 + col];

    const float bhn = dec_bhh[512 + col];
    const int vcol = wv * 16 + l15;
    const int orow = (vcol < VOCAB) ? vcol : (VOCAB - 1);
    const float ob = (wv < 7 && vcol < VOCAB) ? out_b[vcol] : 0.0f;
    const f32x4 z4 = {0.f, 0.f, 0.f, 0.f};

    #pragma unroll 1
    for (int t = 0; t < TT; ++t) {
        const _Float16* rh = s_hb[t & 1];
        _Float16* wh = s_hb[(t + 1) & 1];

        f32x4 a0 = z4, a1 = z4, a2 = z4, aco = z4;
        #pragma unroll
        for (int ks = 0; ks < 8; ++ks) {
            f16x8 a = *(const f16x8*)(rh + l15 * H_LD + ks * 32 + lgrp * 8);
            a0 = __builtin_amdgcn_mfma_f32_16x16x32_f16(a, Breg[0][ks], a0, 0, 0, 0);
            a1 = __builtin_amdgcn_mfma_f32_16x16x32_f16(a, Breg[1][ks], a1, 0, 0, 0);
            a2 = __builtin_amdgcn_mfma_f32_16x16x32_f16(a, Breg[2][ks], a2, 0, 0, 0);
            if (wv < 7) {
                f16x8 wo = *(const f16x8*)(s_outw + orow * 512 + ((ks * 64 + lgrp * 16) ^ ((orow & 7) << 4)));
                aco = __builtin_amdgcn_mfma_f32_16x16x32_f16(a, wo, aco, 0, 0, 0);
            }
        }
        if (t > 0 && wv < 7 && vcol < VOCAB) {
            size_t base = (size_t)(bbase + lgrp * 4) * LROW + (size_t)(t - 1) * VOCAB + vcol;
            #pragma unroll
            for (int j = 0; j < 4; ++j) out[base + (size_t)j * LROW] = aco[j] + ob;
        }
        #pragma unroll
        for (int j = 0; j < 4; ++j) {
            const int row = lgrp * 4 + j;
            f16x4 q = s_zp[col * ZP_LD + lgrp * 4 + j];
            float rg = sigf(a0[j] + (float)q[0]);
            float zg = sigf(a1[j] + (float)q[1]);
            float n  = tanh_f((float)q[2] + rg * (a2[j] + bhn));
            float h  = n + zg * (hpr[j] - n);
            hpr[j] = h;
            wh[row * H_LD + col] = (_Float16)h;
        }
        barrier_lgkm();
    }

    if (wv < 7) {
        const _Float16* rh = s_hb[0];
        f32x4 aco = z4;
        #pragma unroll
        for (int ks = 0; ks < 8; ++ks) {
            f16x8 a  = *(const f16x8*)(rh + l15 * H_LD + ks * 32 + lgrp * 8);
            f16x8 wo = *(const f16x8*)(s_outw + orow * 512 + ((ks * 64 + lgrp * 16) ^ ((orow & 7) << 4)));
            aco = __builtin_amdgcn_mfma_f32_16x16x32_f16(a, wo, aco, 0, 0, 0);
        }
        if (vcol < VOCAB) {
            size_t base = (size_t)(bbase + lgrp * 4) * LROW + (size_t)(TT - 1) * VOCAB + vcol;
            #pragma unroll
            for (int j = 0; j < 4; ++j) out[base + (size_t)j * LROW] = aco[j] + ob;
        }
    }
}

extern "C" void kernel_launch(void* const* d_in, const int* in_sizes, int n_in,
                              void* d_out, int out_size, void* d_ws, size_t ws_size,
                              hipStream_t stream) {
    const int*   x       = (const int*)  d_in[0];
    const float* eps     = (const float*)d_in[1];
    const float* emb     = (const float*)d_in[2];
    const float* enc_Wih = (const float*)d_in[3];
    const float* enc_Whh = (const float*)d_in[4];
    const float* enc_bih = (const float*)d_in[5];
    const float* enc_bhh = (const float*)d_in[6];
    const float* mu_W    = (const float*)d_in[7];
    const float* mu_b    = (const float*)d_in[8];
    const float* lv_W    = (const float*)d_in[9];
    const float* lv_b    = (const float*)d_in[10];
    const float* di_W    = (const float*)d_in[11];
    const float* di_b    = (const float*)d_in[12];
    const float* dec_Wih = (const float*)d_in[13];
    const float* dec_Whh = (const float*)d_in[14];
    const float* dec_bih = (const float*)d_in[15];
    const float* dec_bhh = (const float*)d_in[16];
    const float* out_W   = (const float*)d_in[17];
    const float* out_b   = (const float*)d_in[18];
    float* out = (float*)d_out;

    _Float16* PT = (_Float16*)d_ws;                                  // [100][768] f16
    const size_t HOFFB = 153600;
    _Float16* Hbuf = (_Float16*)((char*)d_ws + HOFFB);               // [BB*TT][256] f16
    const size_t need = HOFFB + (size_t)BB * TT * 256 * sizeof(_Float16);

    pt_kernel<<<VOCAB, 256, 0, stream>>>(emb, enc_Wih, enc_bih, enc_bhh, PT);
    enc_kernel<<<BB / ROWS, 1024, 0, stream>>>(x, PT, enc_Whh, enc_bhh, out);
    if (ws_size >= need) {
        dec_rnn_kernel<<<BB / ROWS, 1024, 0, stream>>>(eps, mu_W, mu_b, lv_W, lv_b,
            di_W, di_b, dec_Wih, dec_Whh, dec_bih, dec_bhh, out, Hbuf);
        logits_kernel<<<(BB * TT / 16) / 32, 1024, 0, stream>>>(Hbuf, out_W, out_b, out);
    } else {
        dec_fused_kernel<<<BB / 16, 1024, 0, stream>>>(eps, mu_W, mu_b, lv_W, lv_b,
            di_W, di_b, dec_Wih, dec_Whh, dec_bih, dec_bhh, out_W, out_b, out);
    }
}

// Round 10
// 1108.873 us; speedup vs baseline: 5.1650x; 5.1650x over previous
//
#include <hip/hip_runtime.h>
#include <hip/hip_bf16.h>

#define VOCAB 100
#define EDIM  128
#define HDIM  256
#define LDIM  64
#define G3    768
#define TT    128
#define BB    4096
#define LROW  (TT * VOCAB)
#define H_LD  264            // halfs per h-row (256 + 8 pad)
#define ZP_LD 17             // f16x4 units per zp col (16 rows + 1 pad)

typedef float    f32x4 __attribute__((ext_vector_type(4)));
typedef _Float16 f16x8 __attribute__((ext_vector_type(8)));
typedef _Float16 f16x4 __attribute__((ext_vector_type(4)));

__device__ __forceinline__ float sigf(float x) {
    return __builtin_amdgcn_rcpf(1.0f + __expf(-x));
}
__device__ __forceinline__ float tanh_f(float x) {
    return 2.0f * __builtin_amdgcn_rcpf(1.0f + __expf(-2.0f * x)) - 1.0f;
}
__device__ __forceinline__ void barrier_lgkm() {
    asm volatile("s_waitcnt lgkmcnt(0)\n\ts_barrier" ::: "memory");
}
__device__ __forceinline__ f16x8 ld_bfrag(const float* __restrict__ W, int outcol, int ks, int lgrp) {
    const float* p = W + outcol * HDIM + ks * 32 + lgrp * 8;
    float4 a = *(const float4*)p;
    float4 b = *(const float4*)(p + 4);
    f16x8 w = {(_Float16)a.x, (_Float16)a.y, (_Float16)a.z, (_Float16)a.w,
               (_Float16)b.x, (_Float16)b.y, (_Float16)b.z, (_Float16)b.w};
    return w;
}

// ---------------- prep: PT2[v][g] = enc_Wih@emb[v] + enc_bih + (g<512 ? enc_bhh : 0), f16 ----------------
__global__ void pt_kernel(const float* __restrict__ emb, const float* __restrict__ Wih,
                          const float* __restrict__ bih, const float* __restrict__ bhh,
                          _Float16* __restrict__ PT) {
    int v = blockIdx.x;
    __shared__ float se[EDIM];
    for (int e = threadIdx.x; e < EDIM; e += blockDim.x) se[e] = emb[v * EDIM + e];
    __syncthreads();
    for (int g = threadIdx.x; g < G3; g += blockDim.x) {
        const float* wr = Wih + g * EDIM;
        float acc = bih[g] + (g < 512 ? bhh[g] : 0.0f);
        #pragma unroll 8
        for (int e = 0; e < EDIM; ++e) acc += se[e] * wr[e];
        PT[v * G3 + g] = (_Float16)acc;
    }
}

// ===================================================================
// ENCODER: 16 rows/block, (1024,4). Gate-input gathers issued at step
// TOP (hide under MFMA); next-step token prefetched during gates.
// ===================================================================
__global__ __launch_bounds__(1024, 4) void enc_kernel(
    const int* __restrict__ x, const _Float16* __restrict__ PT2,
    const float* __restrict__ Whh, const float* __restrict__ bhh,
    float* __restrict__ out)
{
    __shared__ _Float16 s_h[2][16 * H_LD];
    __shared__ int s_tok[16 * TT];

    const int tid  = threadIdx.x;
    const int lane = tid & 63;
    const int wv   = tid >> 6;
    const int l15  = lane & 15;
    const int lgrp = lane >> 4;
    const int bbase = blockIdx.x * 16;
    const int col  = wv * 16 + l15;

    for (int i = tid; i < 16 * TT; i += 1024) s_tok[i] = x[bbase * TT + i];

    f16x8 Breg[3][8];
    #pragma unroll
    for (int g = 0; g < 3; ++g)
        #pragma unroll
        for (int ks = 0; ks < 8; ++ks)
            Breg[g][ks] = ld_bfrag(Whh, g * 256 + col, ks, lgrp);

    const float bhn = bhh[512 + col];
    float hst[4] = {0.f, 0.f, 0.f, 0.f};

    for (int i = tid; i < 16 * H_LD; i += 1024) s_h[0][i] = (_Float16)0.f;
    __syncthreads();

    int tokp[4];
    #pragma unroll
    for (int j = 0; j < 4; ++j) tokp[j] = s_tok[(lgrp * 4 + j) * TT];

    const f32x4 z4 = {0.f, 0.f, 0.f, 0.f};

    #pragma unroll 1
    for (int t = 0; t < TT; ++t) {
        const _Float16* rh = s_h[t & 1];
        _Float16* wh = s_h[(t + 1) & 1];

        // issue gate-input gathers FIRST: latency hides under the MFMA phase
        _Float16 pr[4], pz[4], pn[4];
        #pragma unroll
        for (int j = 0; j < 4; ++j) {
            const _Float16* p = PT2 + tokp[j] * G3 + col;
            pr[j] = p[0]; pz[j] = p[256]; pn[j] = p[512];
        }

        f32x4 a0 = z4, a1 = z4, a2 = z4;
        #pragma unroll
        for (int ks = 0; ks < 8; ++ks) {
            f16x8 a = *(const f16x8*)(rh + l15 * H_LD + ks * 32 + lgrp * 8);
            a0 = __builtin_amdgcn_mfma_f32_16x16x32_f16(a, Breg[0][ks], a0, 0, 0, 0);
            a1 = __builtin_amdgcn_mfma_f32_16x16x32_f16(a, Breg[1][ks], a1, 0, 0, 0);
            a2 = __builtin_amdgcn_mfma_f32_16x16x32_f16(a, Breg[2][ks], a2, 0, 0, 0);
        }

        // prefetch next-step tokens (LDS) while gates run
        if (t + 1 < TT) {
            #pragma unroll
            for (int j = 0; j < 4; ++j) tokp[j] = s_tok[(lgrp * 4 + j) * TT + t + 1];
        }

        #pragma unroll
        for (int j = 0; j < 4; ++j) {
            const int row = lgrp * 4 + j;
            float rg = sigf(a0[j] + (float)pr[j]);
            float zg = sigf(a1[j] + (float)pz[j]);
            float n  = tanh_f((float)pn[j] + rg * (a2[j] + bhn));
            float h  = n + zg * (hst[j] - n);
            hst[j] = h;
            wh[row * H_LD + col] = (_Float16)h;
            if (t == TT - 1) out[(size_t)(bbase + row) * LROW + col] = h;
        }
        barrier_lgkm();
    }
}

// ===================================================================
// DECODER RNN: 16 rows/block, (1024,4). zp hoisted into REGISTERS
// (t-invariant!) -> gate phase has zero memory operands. Streams h_t
// to Hbuf with all 1024 threads (16 rows x 64 segs).
// ===================================================================
__global__ __launch_bounds__(1024, 4) void dec_rnn_kernel(
    const float* __restrict__ eps,
    const float* __restrict__ mu_W, const float* __restrict__ mu_b,
    const float* __restrict__ lv_W, const float* __restrict__ lv_b,
    const float* __restrict__ di_W, const float* __restrict__ di_b,
    const float* __restrict__ dec_Wih, const float* __restrict__ dec_Whh,
    const float* __restrict__ dec_bih, const float* __restrict__ dec_bhh,
    float* __restrict__ out, _Float16* __restrict__ Hbuf)
{
    __shared__ _Float16 s_hb[2][16 * H_LD];   // 16896 B
    __shared__ f16x4 s_zp[256 * ZP_LD];       // 34816 B {r,z,n,_}
    __shared__ float s_hl[16 * 260];          // 16640 B

    const int tid  = threadIdx.x;
    const int lane = tid & 63;
    const int wv   = tid >> 6;
    const int l15  = lane & 15;
    const int lgrp = lane >> 4;
    const int bbase = blockIdx.x * 16;
    const int col  = wv * 16 + l15;

    for (int i = tid; i < 16 * HDIM; i += 1024) {
        int m = i >> 8, c = i & 255;
        s_hl[m * 260 + c] = out[(size_t)(bbase + m) * LROW + c];
    }

    f16x8 Breg[3][8];
    #pragma unroll
    for (int g = 0; g < 3; ++g)
        #pragma unroll
        for (int ks = 0; ks < 8; ++ks)
            Breg[g][ks] = ld_bfrag(dec_Whh, g * 256 + col, ks, lgrp);
    __syncthreads();

    // ---- mu / logvar / z : one (m,j) per thread ----
    float zv;
    {
        const size_t MU_OFF = (size_t)BB * TT * VOCAB;
        const size_t LV_OFF = MU_OFF + (size_t)BB * LDIM;
        int m = tid >> 6, j = tid & 63;
        const float* mwr = mu_W + j * HDIM;
        const float* lwr = lv_W + j * HDIM;
        float am = mu_b[j], al = lv_b[j];
        #pragma unroll 4
        for (int k = 0; k < HDIM; ++k) { float hv = s_hl[m * 260 + k]; am += hv * mwr[k]; al += hv * lwr[k]; }
        size_t bo = (size_t)(bbase + m) * LDIM + j;
        out[MU_OFF + bo] = am;
        out[LV_OFF + bo] = al;
        zv = am + eps[bo] * __expf(0.5f * al);
    }
    __syncthreads();                 // all h_last reads done
    { int m = tid >> 6, j = tid & 63; s_hl[m * 260 + j] = zv; }
    __syncthreads();                 // z staged (cols 0..63)

    // ---- hidden = tanh(di_W z + di_b); zp = dec_Wih z + dec_bih (+bhh r,z) ----
    {
        const int gc = tid & 255;
        const int gm = tid >> 8;     // 0..3 -> rows gm*4..+4
        float ah[4], ar[4], az[4], an[4];
        float dib = di_b[gc];
        float bir = dec_bih[gc], biz = dec_bih[gc + 256], bin_ = dec_bih[gc + 512];
        #pragma unroll
        for (int i = 0; i < 4; ++i) { ah[i] = dib; ar[i] = bir; az[i] = biz; an[i] = bin_; }
        const float* w0 = di_W + gc * LDIM;
        const float* w1 = dec_Wih + gc * LDIM;
        const float* w2 = dec_Wih + (gc + 256) * LDIM;
        const float* w3 = dec_Wih + (gc + 512) * LDIM;
        #pragma unroll 2
        for (int j = 0; j < LDIM; ++j) {
            float a0 = w0[j], a1 = w1[j], a2 = w2[j], a3 = w3[j];
            #pragma unroll
            for (int i = 0; i < 4; ++i) {
                float q = s_hl[(gm * 4 + i) * 260 + j];
                ah[i] += q * a0; ar[i] += q * a1; az[i] += q * a2; an[i] += q * a3;
            }
        }
        float bhr = dec_bhh[gc], bhz = dec_bhh[gc + 256];
        __syncthreads();             // z reads done before s_hl overwrite
        #pragma unroll
        for (int i = 0; i < 4; ++i) {
            int r = gm * 4 + i;
            float th = tanh_f(ah[i]);
            s_hl[r * 260 + gc] = th;
            f16x4 q = {(_Float16)(ar[i] + bhr), (_Float16)(az[i] + bhz), (_Float16)an[i], (_Float16)0.f};
            s_zp[gc * ZP_LD + r] = q;
            s_hb[0][r * H_LD + gc] = (_Float16)th;
        }
    }
    __syncthreads();                 // th/zp/h0 staged

    float hpr[4];
    #pragma unroll
    for (int j = 0; j < 4; ++j) hpr[j] = s_hl[(lgrp * 4 + j) * 260 + col];

    // HOIST zp into registers — t-invariant, so the loop's gate phase
    // has no memory operands at all.
    f16x4 zq[4];
    #pragma unroll
    for (int j = 0; j < 4; ++j) zq[j] = s_zp[col * ZP_LD + lgrp * 4 + j];

    const float bhn = dec_bhh[512 + col];
    const f32x4 z4 = {0.f, 0.f, 0.f, 0.f};
    const int crow = tid >> 6;       // 0..15: full 16-row Hbuf coverage
    const int cseg = lane;           // 0..63
    _Float16* hb = Hbuf + ((size_t)(bbase + crow) * TT) * 256 + cseg * 4;
    const int lread = crow * H_LD + cseg * 4;

    #pragma unroll 1
    for (int t = 0; t < TT; ++t) {
        const _Float16* rh = s_hb[t & 1];
        _Float16* wh = s_hb[(t + 1) & 1];

        f32x4 a0 = z4, a1 = z4, a2 = z4;
        #pragma unroll
        for (int ks = 0; ks < 8; ++ks) {
            f16x8 a = *(const f16x8*)(rh + l15 * H_LD + ks * 32 + lgrp * 8);
            a0 = __builtin_amdgcn_mfma_f32_16x16x32_f16(a, Breg[0][ks], a0, 0, 0, 0);
            a1 = __builtin_amdgcn_mfma_f32_16x16x32_f16(a, Breg[1][ks], a1, 0, 0, 0);
            a2 = __builtin_amdgcn_mfma_f32_16x16x32_f16(a, Breg[2][ks], a2, 0, 0, 0);
        }
        #pragma unroll
        for (int j = 0; j < 4; ++j) {
            const int row = lgrp * 4 + j;
            f16x4 q = zq[j];
            float rg = sigf(a0[j] + (float)q[0]);
            float zg = sigf(a1[j] + (float)q[1]);
            float n  = tanh_f((float)q[2] + rg * (a2[j] + bhn));
            float h  = n + zg * (hpr[j] - n);
            hpr[j] = h;
            wh[row * H_LD + col] = (_Float16)h;
        }
        barrier_lgkm();
        // stream h_{t+1} (logits row s=t): 8 KB coalesced, stays in vmcnt flight
        *(f16x4*)hb = *(const f16x4*)(wh + lread);
        hb += 256;
    }
}

// ===================================================================
// LOGITS GEMM (R9, verified): LDS-staged LINEAR copy-out, no RMW.
// ===================================================================
__global__ __launch_bounds__(1024, 4) void logits_kernel(
    const _Float16* __restrict__ Hbuf, const float* __restrict__ out_W,
    const float* __restrict__ out_b, float* __restrict__ out)
{
    __shared__ __attribute__((aligned(16))) unsigned char s_outw[VOCAB * 512]; // 51200 B
    __shared__ __attribute__((aligned(16))) float s_ls[256 * 108];             // 110592 B
    const int tid = threadIdx.x, lane = tid & 63, wv = tid >> 6;
    const int l15 = lane & 15, lgrp = lane >> 4;

    for (int idx = tid; idx < VOCAB * HDIM; idx += 1024) {
        int r = idx >> 8, k = idx & 255;
        _Float16 w = (_Float16)out_W[r * 256 + k];
        *(short*)(s_outw + r * 512 + ((2 * k) ^ ((r & 7) << 4))) = __builtin_bit_cast(short, w);
    }
    __syncthreads();

    float ob[7];
    #pragma unroll
    for (int vt = 0; vt < 7; ++vt) {
        int v = vt * 16 + l15;
        ob[vt] = (v < VOCAB) ? out_b[v] : 0.0f;
    }
    const f32x4 z4 = {0.f, 0.f, 0.f, 0.f};

    #pragma unroll 1
    for (int round = 0; round < 2; ++round) {
        size_t mt = (size_t)blockIdx.x * 32 + round * 16 + wv;   // 16-row tile index
        const _Float16* hrow = Hbuf + (mt * 16 + l15) * 256;
        f32x4 acc[7];
        #pragma unroll
        for (int vt = 0; vt < 7; ++vt) acc[vt] = z4;
        #pragma unroll
        for (int ks = 0; ks < 8; ++ks) {
            f16x8 a = *(const f16x8*)(hrow + ks * 32 + lgrp * 8);
            #pragma unroll
            for (int vt = 0; vt < 7; ++vt) {
                int orow = vt * 16 + l15; if (orow > VOCAB - 1) orow = VOCAB - 1;
                f16x8 wo = *(const f16x8*)(s_outw + orow * 512 + ((ks * 64 + lgrp * 16) ^ ((orow & 7) << 4)));
                acc[vt] = __builtin_amdgcn_mfma_f32_16x16x32_f16(a, wo, acc[vt], 0, 0, 0);
            }
        }
        #pragma unroll
        for (int vt = 0; vt < 7; ++vt) {
            int v = vt * 16 + l15;
            if (v < VOCAB) {
                #pragma unroll
                for (int j = 0; j < 4; ++j)
                    s_ls[(wv * 16 + lgrp * 4 + j) * 108 + v] = acc[vt][j] + ob[vt];
            }
        }
        __syncthreads();
        {
            size_t slabM0 = (size_t)blockIdx.x * 512 + round * 256;
            float* gbase = out + slabM0 * VOCAB;
            for (int c = tid; c < 6400; c += 1024) {
                int r = c / 25, cc = (c % 25) * 4;
                f32x4 vch = *(const f32x4*)(s_ls + r * 108 + cc);
                *(f32x4*)(gbase + (size_t)c * 4) = vch;
            }
        }
        __syncthreads();
    }
}

// ===================================================================
// FALLBACK fused decoder (R6, known-passing) — used if ws too small.
// ===================================================================
__global__ __launch_bounds__(1024, 4) void dec_fused_kernel(
    const float* __restrict__ eps,
    const float* __restrict__ mu_W, const float* __restrict__ mu_b,
    const float* __restrict__ lv_W, const float* __restrict__ lv_b,
    const float* __restrict__ di_W, const float* __restrict__ di_b,
    const float* __restrict__ dec_Wih, const float* __restrict__ dec_Whh,
    const float* __restrict__ dec_bih, const float* __restrict__ dec_bhh,
    const float* __restrict__ out_W, const float* __restrict__ out_b,
    float* __restrict__ out)
{
    __shared__ _Float16 s_hb[2][16 * H_LD];
    __shared__ f16x4 s_zp[256 * ZP_LD];
    __shared__ __attribute__((aligned(16))) unsigned char s_outw[VOCAB * 512];
    __shared__ float s_hl[16 * 260];

    const int tid  = threadIdx.x;
    const int lane = tid & 63;
    const int wv   = tid >> 6;
    const int l15  = lane & 15;
    const int lgrp = lane >> 4;
    const int bbase = blockIdx.x * 16;
    const int col  = wv * 16 + l15;

    for (int i = tid; i < 16 * HDIM; i += 1024) {
        int m = i >> 8, c = i & 255;
        s_hl[m * 260 + c] = out[(size_t)(bbase + m) * LROW + c];
    }
    for (int idx = tid; idx < VOCAB * HDIM; idx += 1024) {
        int r = idx >> 8, k = idx & 255;
        _Float16 w = (_Float16)out_W[r * 256 + k];
        *(short*)(s_outw + r * 512 + ((2 * k) ^ ((r & 7) << 4))) = __builtin_bit_cast(short, w);
    }

    f16x8 Breg[3][8];
    #pragma unroll
    for (int g = 0; g < 3; ++g)
        #pragma unroll
        for (int ks = 0; ks < 8; ++ks)
            Breg[g][ks] = ld_bfrag(dec_Whh, g * 256 + col, ks, lgrp);
    __syncthreads();

    float zv;
    {
        const size_t MU_OFF = (size_t)BB * TT * VOCAB;
        const size_t LV_OFF = MU_OFF + (size_t)BB * LDIM;
        int m = tid >> 6, j = tid & 63;
        const float* mwr = mu_W + j * HDIM;
        const float* lwr = lv_W + j * HDIM;
        float am = mu_b[j], al = lv_b[j];
        #pragma unroll 4
        for (int k = 0; k < HDIM; ++k) { float hv = s_hl[m * 260 + k]; am += hv * mwr[k]; al += hv * lwr[k]; }
        size_t bo = (size_t)(bbase + m) * LDIM + j;
        out[MU_OFF + bo] = am;
        out[LV_OFF + bo] = al;
        zv = am + eps[bo] * __expf(0.5f * al);
    }
    __syncthreads();
    { int m = tid >> 6, j = tid & 63; s_hl[m * 260 + j] = zv; }
    __syncthreads();

    float th[4];
    {
        const int gc = tid & 255;
        const int gm = tid >> 8;
        float ah[4], ar[4], az[4], an[4];
        float dib = di_b[gc];
        float bir = dec_bih[gc], biz = dec_bih[gc + 256], bin_ = dec_bih[gc + 512];
        #pragma unroll
        for (int i = 0; i < 4; ++i) { ah[i] = dib; ar[i] = bir; az[i] = biz; an[i] = bin_; }
        const float* w0 = di_W + gc * LDIM;
        const float* w1 = dec_Wih + gc * LDIM;
        const float* w2 = dec_Wih + (gc + 256) * LDIM;
        const float* w3 = dec_Wih + (gc + 512) * LDIM;
        #pragma unroll 2
        for (int j = 0; j < LDIM; ++j) {
            float a0 = w0[j], a1 = w1[j], a2 = w2[j], a3 = w3[j];
            #pragma unroll
            for (int i = 0; i < 4; ++i) {
                float q = s_hl[(gm * 4 + i) * 260 + j];
                ah[i] += q * a0; ar[i] += q * a1; az[i] += q * a2; an[i] += q * a3;
            }
        }
        float bhr = dec_bhh[gc], bhz = dec_bhh[gc + 256];
        __syncthreads();
        #pragma unroll
        for (int i = 0; i < 4; ++i) {
            int r = gm * 4 + i;
            th[i] = tanh_f(ah[i]);
            s_hl[r * 260 + gc] = th[i];
            f16x4 q = {(_Float16)(ar[i] + bhr), (_Float16)(az[i] + bhz), (_Float16)an[i], (_Float16)0.f};
            s_zp[gc * ZP_LD + r] = q;
            s_hb[0][r * H_LD + gc] = (_Float16)th[i];
        }
    }
    __syncthreads();

    float hpr[4];
    #pragma unroll
    for (int j = 0; j < 4; ++j) hpr[j] = s_hl[(lgrp * 4 + j) * 260 + col];

    const float bhn = dec_bhh[512 + col];
    const int vcol = wv * 16 + l15;
    const int orow = (vcol < VOCAB) ? vcol : (VOCAB - 1);
    const float ob = (wv < 7 && vcol < VOCAB) ? out_b[vcol] : 0.0f;
    const f32x4 z4 = {0.f, 0.f, 0.f, 0.f};

    #pragma unroll 1
    for (int t = 0; t < TT; ++t) {
        const _Float16* rh = s_hb[t & 1];
        _Float16* wh = s_hb[(t + 1) & 1];

        f32x4 a0 = z4, a1 = z4, a2 = z4, aco = z4;
        #pragma unroll
        for (int ks = 0; ks < 8; ++ks) {
            f16x8 a = *(const f16x8*)(rh + l15 * H_LD + ks * 32 + lgrp * 8);
            a0 = __builtin_amdgcn_mfma_f32_16x16x32_f16(a, Breg[0][ks], a0, 0, 0, 0);
            a1 = __builtin_amdgcn_mfma_f32_16x16x32_f16(a, Breg[1][ks], a1, 0, 0, 0);
            a2 = __builtin_amdgcn_mfma_f32_16x16x32_f16(a, Breg[2][ks], a2, 0, 0, 0);
            if (wv < 7) {
                f16x8 wo = *(const f16x8*)(s_outw + orow * 512 + ((ks * 64 + lgrp * 16) ^ ((orow & 7) << 4)));
                aco = __builtin_amdgcn_mfma_f32_16x16x32_f16(a, wo, aco, 0, 0, 0);
            }
        }
        if (t > 0 && wv < 7 && vcol < VOCAB) {
            size_t base = (size_t)(bbase + lgrp * 4) * LROW + (size_t)(t - 1) * VOCAB + vcol;
            #pragma unroll
            for (int j = 0; j < 4; ++j) out[base + (size_t)j * LROW] = aco[j] + ob;
        }
        #pragma unroll
        for (int j = 0; j < 4; ++j) {
            const int row = lgrp * 4 + j;
            f16x4 q = s_zp[col * ZP_LD + lgrp * 4 + j];
            float rg = sigf(a0[j] + (float)q[0]);
            float zg = sigf(a1[j] + (float)q[1]);
            float n  = tanh_f((float)q[2] + rg * (a2[j] + bhn));
            float h  = n + zg * (hpr[j] - n);
            hpr[j] = h;
            wh[row * H_LD + col] = (_Float16)h;
        }
        barrier_lgkm();
    }

    if (wv < 7) {
        const _Float16* rh = s_hb[0];
        f32x4 aco = z4;
        #pragma unroll
        for (int ks = 0; ks < 8; ++ks) {
            f16x8 a  = *(const f16x8*)(rh + l15 * H_LD + ks * 32 + lgrp * 8);
            f16x8 wo = *(const f16x8*)(s_outw + orow * 512 + ((ks * 64 + lgrp * 16) ^ ((orow & 7) << 4)));
            aco = __builtin_amdgcn_mfma_f32_16x16x32_f16(a, wo, aco, 0, 0, 0);
        }
        if (vcol < VOCAB) {
            size_t base = (size_t)(bbase + lgrp * 4) * LROW + (size_t)(TT - 1) * VOCAB + vcol;
            #pragma unroll
            for (int j = 0; j < 4; ++j) out[base + (size_t)j * LROW] = aco[j] + ob;
        }
    }
}

extern "C" void kernel_launch(void* const* d_in, const int* in_sizes, int n_in,
                              void* d_out, int out_size, void* d_ws, size_t ws_size,
                              hipStream_t stream) {
    const int*   x       = (const int*)  d_in[0];
    const float* eps     = (const float*)d_in[1];
    const float* emb     = (const float*)d_in[2];
    const float* enc_Wih = (const float*)d_in[3];
    const float* enc_Whh = (const float*)d_in[4];
    const float* enc_bih = (const float*)d_in[5];
    const float* enc_bhh = (const float*)d_in[6];
    const float* mu_W    = (const float*)d_in[7];
    const float* mu_b    = (const float*)d_in[8];
    const float* lv_W    = (const float*)d_in[9];
    const float* lv_b    = (const float*)d_in[10];
    const float* di_W    = (const float*)d_in[11];
    const float* di_b    = (const float*)d_in[12];
    const float* dec_Wih = (const float*)d_in[13];
    const float* dec_Whh = (const float*)d_in[14];
    const float* dec_bih = (const float*)d_in[15];
    const float* dec_bhh = (const float*)d_in[16];
    const float* out_W   = (const float*)d_in[17];
    const float* out_b   = (const float*)d_in[18];
    float* out = (float*)d_out;

    _Float16* PT = (_Float16*)d_ws;                                  // [100][768] f16
    const size_t HOFFB = 153600;
    _Float16* Hbuf = (_Float16*)((char*)d_ws + HOFFB);               // [BB*TT][256] f16
    const size_t need = HOFFB + (size_t)BB * TT * 256 * sizeof(_Float16);

    pt_kernel<<<VOCAB, 256, 0, stream>>>(emb, enc_Wih, enc_bih, enc_bhh, PT);
    enc_kernel<<<BB / 16, 1024, 0, stream>>>(x, PT, enc_Whh, enc_bhh, out);
    if (ws_size >= need) {
        dec_rnn_kernel<<<BB / 16, 1024, 0, stream>>>(eps, mu_W, mu_b, lv_W, lv_b,
            di_W, di_b, dec_Wih, dec_Whh, dec_bih, dec_bhh, out, Hbuf);
        logits_kernel<<<(BB * TT / 16) / 32, 1024, 0, stream>>>(Hbuf, out_W, out_b, out);
    } else {
        dec_fused_kernel<<<BB / 16, 1024, 0, stream>>>(eps, mu_W, mu_b, lv_W, lv_b,
            di_W, di_b, dec_Wih, dec_Whh, dec_bih, dec_bhh, out_W, out_b, out);
    }
}

// Round 11
// 940.555 us; speedup vs baseline: 6.0893x; 1.1790x over previous
//
#include <hip/hip_runtime.h>
#include <hip/hip_bf16.h>

#define VOCAB 100
#define EDIM  128
#define HDIM  256
#define LDIM  64
#define G3    768
#define TT    128
#define BB    4096
#define LROW  (TT * VOCAB)
#define H_LD  264            // halfs per h-row (256 + 8 pad)
#define ZP_LD 17             // f16x4 units per zp col (16 rows + 1 pad)

typedef float    f32x4 __attribute__((ext_vector_type(4)));
typedef _Float16 f16x8 __attribute__((ext_vector_type(8)));
typedef _Float16 f16x4 __attribute__((ext_vector_type(4)));

__device__ __forceinline__ float sigf(float x) {
    return __builtin_amdgcn_rcpf(1.0f + __expf(-x));
}
__device__ __forceinline__ float tanh_f(float x) {
    return 2.0f * __builtin_amdgcn_rcpf(1.0f + __expf(-2.0f * x)) - 1.0f;
}
__device__ __forceinline__ void barrier_lgkm() {
    asm volatile("s_waitcnt lgkmcnt(0)\n\ts_barrier" ::: "memory");
}
__device__ __forceinline__ unsigned short h2b(_Float16 h) {
    return __builtin_bit_cast(unsigned short, h);
}

// B fragment for the K-PERMUTED h layout (R3-verified):
// physical k p -> logical k_log = (p&~31) | ((p&1)<<4) | ((p&31)>>1)
__device__ __forceinline__ f16x8 ld_bfragK(const float* __restrict__ W, int outcol, int ks, int lgrp) {
    const float* p = W + outcol * HDIM + ks * 32 + lgrp * 4;
    float4 f0 = *(const float4*)p;
    float4 f1 = *(const float4*)(p + 16);
    f16x8 w = {(_Float16)f0.x, (_Float16)f1.x, (_Float16)f0.y, (_Float16)f1.y,
               (_Float16)f0.z, (_Float16)f1.z, (_Float16)f0.w, (_Float16)f1.w};
    return w;
}

// ---------------- prep: PT2[v][g] = enc_Wih@emb[v] + enc_bih + (g<512 ? enc_bhh : 0), f16 ----------------
__global__ void pt_kernel(const float* __restrict__ emb, const float* __restrict__ Wih,
                          const float* __restrict__ bih, const float* __restrict__ bhh,
                          _Float16* __restrict__ PT) {
    int v = blockIdx.x;
    __shared__ float se[EDIM];
    for (int e = threadIdx.x; e < EDIM; e += blockDim.x) se[e] = emb[v * EDIM + e];
    __syncthreads();
    for (int g = threadIdx.x; g < G3; g += blockDim.x) {
        const float* wr = Wih + g * EDIM;
        float acc = bih[g] + (g < 512 ? bhh[g] : 0.0f);
        #pragma unroll 8
        for (int e = 0; e < EDIM; ++e) acc += se[e] * wr[e];
        PT[v * G3 + g] = (_Float16)acc;
    }
}

// ===================================================================
// ENCODER: 512 thr / 8 waves, 16 rows/block. Wave wv owns logical cols
// {wv*32+l15, +16} x 3 gates -> Breg 192 VGPRs under the 256-reg cap.
// K-permuted h layout; gathers issued at step top.
// ===================================================================
__global__ __launch_bounds__(512, 2) void enc_kernel(
    const int* __restrict__ x, const _Float16* __restrict__ PT2,
    const float* __restrict__ Whh, const float* __restrict__ bhh,
    float* __restrict__ out)
{
    __shared__ _Float16 s_h[2][16 * H_LD];   // 16896 B
    __shared__ int s_tok[16 * TT];           // 8192 B

    const int tid  = threadIdx.x;
    const int lane = tid & 63;
    const int wv   = tid >> 6;               // 0..7
    const int l15  = lane & 15;
    const int lgrp = lane >> 4;
    const int bbase = blockIdx.x * 16;
    const int colb = wv * 32 + l15;          // logical col (cg=0); cg=1 is +16

    for (int i = tid; i < 16 * TT; i += 512) s_tok[i] = x[bbase * TT + i];

    f16x8 Breg[3][2][8];
    #pragma unroll
    for (int g = 0; g < 3; ++g)
        #pragma unroll
        for (int cg = 0; cg < 2; ++cg)
            #pragma unroll
            for (int ks = 0; ks < 8; ++ks)
                Breg[g][cg][ks] = ld_bfragK(Whh, g * 256 + colb + cg * 16, ks, lgrp);

    const float bhn0 = bhh[512 + colb];
    const float bhn1 = bhh[528 + colb];

    float hst[4][2];
    #pragma unroll
    for (int j = 0; j < 4; ++j) { hst[j][0] = 0.f; hst[j][1] = 0.f; }

    for (int i = tid; i < 16 * H_LD; i += 512) s_h[0][i] = (_Float16)0.f;
    __syncthreads();

    int tokp[4];
    #pragma unroll
    for (int j = 0; j < 4; ++j) tokp[j] = s_tok[(lgrp * 4 + j) * TT];

    const f32x4 z4 = {0.f, 0.f, 0.f, 0.f};

    #pragma unroll 1
    for (int t = 0; t < TT; ++t) {
        const _Float16* rh = s_h[t & 1];
        _Float16* wh = s_h[(t + 1) & 1];

        // gate-input gathers FIRST: latency hides under the MFMA phase
        _Float16 pr[4][2], pz[4][2], pn[4][2];
        #pragma unroll
        for (int j = 0; j < 4; ++j) {
            const _Float16* p = PT2 + tokp[j] * G3 + colb;
            pr[j][0] = p[0];  pz[j][0] = p[256]; pn[j][0] = p[512];
            pr[j][1] = p[16]; pz[j][1] = p[272]; pn[j][1] = p[528];
        }

        f32x4 acc[3][2];
        #pragma unroll
        for (int g = 0; g < 3; ++g) { acc[g][0] = z4; acc[g][1] = z4; }
        #pragma unroll
        for (int ks = 0; ks < 8; ++ks) {
            f16x8 a = *(const f16x8*)(rh + l15 * H_LD + ks * 32 + lgrp * 8);
            #pragma unroll
            for (int g = 0; g < 3; ++g) {
                acc[g][0] = __builtin_amdgcn_mfma_f32_16x16x32_f16(a, Breg[g][0][ks], acc[g][0], 0, 0, 0);
                acc[g][1] = __builtin_amdgcn_mfma_f32_16x16x32_f16(a, Breg[g][1][ks], acc[g][1], 0, 0, 0);
            }
        }

        if (t + 1 < TT) {
            #pragma unroll
            for (int j = 0; j < 4; ++j) tokp[j] = s_tok[(lgrp * 4 + j) * TT + t + 1];
        }

        #pragma unroll
        for (int j = 0; j < 4; ++j) {
            const int row = lgrp * 4 + j;
            unsigned wpack = 0;
            #pragma unroll
            for (int cg = 0; cg < 2; ++cg) {
                float rg = sigf(acc[0][cg][j] + (float)pr[j][cg]);
                float zg = sigf(acc[1][cg][j] + (float)pz[j][cg]);
                float n  = tanh_f((float)pn[j][cg] + rg * (acc[2][cg][j] + (cg ? bhn1 : bhn0)));
                float h  = n + zg * (hst[j][cg] - n);
                hst[j][cg] = h;
                if (t == TT - 1) out[(size_t)(bbase + row) * LROW + colb + cg * 16] = h;
                wpack |= ((unsigned)h2b((_Float16)h)) << (16 * cg);
            }
            *(unsigned*)(wh + row * H_LD + wv * 32 + 2 * l15) = wpack;
        }
        barrier_lgkm();
    }
}

// ===================================================================
// DECODER RNN: 512 thr / 8 waves, 16 rows/block. Same geometry; zp in
// LDS with bhn folded into slot 3. Streams h_t (K-permuted) to Hbuf.
// ===================================================================
__global__ __launch_bounds__(512, 2) void dec_rnn_kernel(
    const float* __restrict__ eps,
    const float* __restrict__ mu_W, const float* __restrict__ mu_b,
    const float* __restrict__ lv_W, const float* __restrict__ lv_b,
    const float* __restrict__ di_W, const float* __restrict__ di_b,
    const float* __restrict__ dec_Wih, const float* __restrict__ dec_Whh,
    const float* __restrict__ dec_bih, const float* __restrict__ dec_bhh,
    float* __restrict__ out, _Float16* __restrict__ Hbuf)
{
    __shared__ _Float16 s_hb[2][16 * H_LD];   // 16896 B
    __shared__ f16x4 s_zp[256 * ZP_LD];       // 34816 B {r+bhr, z+bhz, n, bhn}
    __shared__ float s_hl[16 * 260];          // 16640 B

    const int tid  = threadIdx.x;
    const int lane = tid & 63;
    const int wv   = tid >> 6;
    const int l15  = lane & 15;
    const int lgrp = lane >> 4;
    const int bbase = blockIdx.x * 16;
    const int colb = wv * 32 + l15;

    for (int i = tid; i < 16 * HDIM; i += 512) {
        int m = i >> 8, c = i & 255;
        s_hl[m * 260 + c] = out[(size_t)(bbase + m) * LROW + c];
    }

    f16x8 Breg[3][2][8];
    #pragma unroll
    for (int g = 0; g < 3; ++g)
        #pragma unroll
        for (int cg = 0; cg < 2; ++cg)
            #pragma unroll
            for (int ks = 0; ks < 8; ++ks)
                Breg[g][cg][ks] = ld_bfragK(dec_Whh, g * 256 + colb + cg * 16, ks, lgrp);
    __syncthreads();

    // ---- mu / logvar / z : 2 outputs per thread ----
    float z0 = 0.f, z1 = 0.f;
    {
        const size_t MU_OFF = (size_t)BB * TT * VOCAB;
        const size_t LV_OFF = MU_OFF + (size_t)BB * LDIM;
        #pragma unroll
        for (int oo = 0; oo < 2; ++oo) {
            int o = tid * 2 + oo;
            int m = o >> 6, j = o & 63;
            const float* mwr = mu_W + j * HDIM;
            const float* lwr = lv_W + j * HDIM;
            float am = mu_b[j], al = lv_b[j];
            #pragma unroll 4
            for (int k = 0; k < HDIM; ++k) { float hv = s_hl[m * 260 + k]; am += hv * mwr[k]; al += hv * lwr[k]; }
            size_t bo = (size_t)(bbase + m) * LDIM + j;
            out[MU_OFF + bo] = am;
            out[LV_OFF + bo] = al;
            float zv = am + eps[bo] * __expf(0.5f * al);
            if (oo == 0) z0 = zv; else z1 = zv;
        }
    }
    __syncthreads();                 // all h_last reads done
    {
        int o0 = tid * 2;
        s_hl[(o0 >> 6) * 260 + (o0 & 63)] = z0;
        int o1 = o0 + 1;
        s_hl[(o1 >> 6) * 260 + (o1 & 63)] = z1;
    }
    __syncthreads();                 // z staged (rows 0..15, cols 0..63)

    // ---- hidden = tanh(di_W z + di_b); zp = dec_Wih z + dec_bih (+bhh r,z; bhn in slot3) ----
    {
        const int gc = tid & 255;
        const int gm2 = tid >> 8;    // 0/1: row parity
        float ah[8], ar[8], az[8], an[8];
        float dib = di_b[gc];
        float bir = dec_bih[gc], biz = dec_bih[gc + 256], bin_ = dec_bih[gc + 512];
        #pragma unroll
        for (int i = 0; i < 8; ++i) { ah[i] = dib; ar[i] = bir; az[i] = biz; an[i] = bin_; }
        const float* w0 = di_W + gc * LDIM;
        const float* w1 = dec_Wih + gc * LDIM;
        const float* w2 = dec_Wih + (gc + 256) * LDIM;
        const float* w3 = dec_Wih + (gc + 512) * LDIM;
        #pragma unroll 2
        for (int j = 0; j < LDIM; ++j) {
            float a0 = w0[j], a1 = w1[j], a2 = w2[j], a3 = w3[j];
            #pragma unroll
            for (int i = 0; i < 8; ++i) {
                float q = s_hl[(gm2 + 2 * i) * 260 + j];
                ah[i] += q * a0; ar[i] += q * a1; az[i] += q * a2; an[i] += q * a3;
            }
        }
        float bhr = dec_bhh[gc], bhz = dec_bhh[gc + 256], bhn_c = dec_bhh[gc + 512];
        __syncthreads();             // z reads done before s_hl overwrite
        int pcol = (gc & ~31) | ((gc & 15) << 1) | ((gc >> 4) & 1);
        #pragma unroll
        for (int i = 0; i < 8; ++i) {
            int m = gm2 + 2 * i;
            float th = tanh_f(ah[i]);
            s_hl[m * 260 + gc] = th;
            f16x4 q = {(_Float16)(ar[i] + bhr), (_Float16)(az[i] + bhz), (_Float16)an[i], (_Float16)bhn_c};
            s_zp[gc * ZP_LD + m] = q;
            s_hb[0][m * H_LD + pcol] = (_Float16)th;
        }
    }
    __syncthreads();                 // th/zp/h0 staged

    float hpr[4][2];
    #pragma unroll
    for (int j = 0; j < 4; ++j) {
        hpr[j][0] = s_hl[(lgrp * 4 + j) * 260 + colb];
        hpr[j][1] = s_hl[(lgrp * 4 + j) * 260 + colb + 16];
    }

    const f32x4 z4 = {0.f, 0.f, 0.f, 0.f};
    const int crow = tid >> 5;       // 0..15
    const int cseg = tid & 31;       // 0..31 (16B chunks)
    _Float16* hb = Hbuf + ((size_t)(bbase + crow) * TT) * 256 + cseg * 8;
    const int lread = crow * H_LD + cseg * 8;

    #pragma unroll 1
    for (int t = 0; t < TT; ++t) {
        const _Float16* rh = s_hb[t & 1];
        _Float16* wh = s_hb[(t + 1) & 1];

        f32x4 acc[3][2];
        #pragma unroll
        for (int g = 0; g < 3; ++g) { acc[g][0] = z4; acc[g][1] = z4; }
        #pragma unroll
        for (int ks = 0; ks < 8; ++ks) {
            f16x8 a = *(const f16x8*)(rh + l15 * H_LD + ks * 32 + lgrp * 8);
            #pragma unroll
            for (int g = 0; g < 3; ++g) {
                acc[g][0] = __builtin_amdgcn_mfma_f32_16x16x32_f16(a, Breg[g][0][ks], acc[g][0], 0, 0, 0);
                acc[g][1] = __builtin_amdgcn_mfma_f32_16x16x32_f16(a, Breg[g][1][ks], acc[g][1], 0, 0, 0);
            }
        }
        #pragma unroll
        for (int j = 0; j < 4; ++j) {
            const int row = lgrp * 4 + j;
            f16x4 q0 = s_zp[colb * ZP_LD + row];
            f16x4 q1 = s_zp[(colb + 16) * ZP_LD + row];
            unsigned wpack = 0;
            #pragma unroll
            for (int cg = 0; cg < 2; ++cg) {
                f16x4 q = cg ? q1 : q0;
                float rg = sigf(acc[0][cg][j] + (float)q[0]);
                float zg = sigf(acc[1][cg][j] + (float)q[1]);
                float n  = tanh_f((float)q[2] + rg * (acc[2][cg][j] + (float)q[3]));
                float h  = n + zg * (hpr[j][cg] - n);
                hpr[j][cg] = h;
                wpack |= ((unsigned)h2b((_Float16)h)) << (16 * cg);
            }
            *(unsigned*)(wh + row * H_LD + wv * 32 + 2 * l15) = wpack;
        }
        barrier_lgkm();
        // stream h_{t+1} (logits row s=t), K-permuted: 8 KB coalesced/block-step
        *(f16x8*)hb = *(const f16x8*)(wh + lread);
        hb += 256;
    }
}

// ===================================================================
// LOGITS GEMM (R9/R10-verified structure): out_W staged with the
// matching K-permute; LDS-staged LINEAR copy-out (no RMW).
// ===================================================================
__global__ __launch_bounds__(1024, 4) void logits_kernel(
    const _Float16* __restrict__ Hbuf, const float* __restrict__ out_W,
    const float* __restrict__ out_b, float* __restrict__ out)
{
    __shared__ __attribute__((aligned(16))) unsigned char s_outw[VOCAB * 512]; // 51200 B
    __shared__ __attribute__((aligned(16))) float s_ls[256 * 108];             // 110592 B
    const int tid = threadIdx.x, lane = tid & 63, wv = tid >> 6;
    const int l15 = lane & 15, lgrp = lane >> 4;

    for (int idx = tid; idx < VOCAB * HDIM; idx += 1024) {
        int r = idx >> 8, kp = idx & 255;
        int kl = (kp & ~31) | ((kp & 1) << 4) | ((kp & 31) >> 1);   // K-permute
        _Float16 w = (_Float16)out_W[r * 256 + kl];
        *(short*)(s_outw + r * 512 + ((2 * kp) ^ ((r & 7) << 4))) = __builtin_bit_cast(short, w);
    }
    __syncthreads();

    float ob[7];
    #pragma unroll
    for (int vt = 0; vt < 7; ++vt) {
        int v = vt * 16 + l15;
        ob[vt] = (v < VOCAB) ? out_b[v] : 0.0f;
    }
    const f32x4 z4 = {0.f, 0.f, 0.f, 0.f};

    #pragma unroll 1
    for (int round = 0; round < 2; ++round) {
        size_t mt = (size_t)blockIdx.x * 32 + round * 16 + wv;   // 16-row tile index
        const _Float16* hrow = Hbuf + (mt * 16 + l15) * 256;
        f32x4 acc[7];
        #pragma unroll
        for (int vt = 0; vt < 7; ++vt) acc[vt] = z4;
        #pragma unroll
        for (int ks = 0; ks < 8; ++ks) {
            f16x8 a = *(const f16x8*)(hrow + ks * 32 + lgrp * 8);
            #pragma unroll
            for (int vt = 0; vt < 7; ++vt) {
                int orow = vt * 16 + l15; if (orow > VOCAB - 1) orow = VOCAB - 1;
                f16x8 wo = *(const f16x8*)(s_outw + orow * 512 + ((ks * 64 + lgrp * 16) ^ ((orow & 7) << 4)));
                acc[vt] = __builtin_amdgcn_mfma_f32_16x16x32_f16(a, wo, acc[vt], 0, 0, 0);
            }
        }
        #pragma unroll
        for (int vt = 0; vt < 7; ++vt) {
            int v = vt * 16 + l15;
            if (v < VOCAB) {
                #pragma unroll
                for (int j = 0; j < 4; ++j)
                    s_ls[(wv * 16 + lgrp * 4 + j) * 108 + v] = acc[vt][j] + ob[vt];
            }
        }
        __syncthreads();
        {
            size_t slabM0 = (size_t)blockIdx.x * 512 + round * 256;
            float* gbase = out + slabM0 * VOCAB;
            for (int c = tid; c < 6400; c += 1024) {
                int r = c / 25, cc = (c % 25) * 4;
                f32x4 vch = *(const f32x4*)(s_ls + r * 108 + cc);
                *(f32x4*)(gbase + (size_t)c * 4) = vch;
            }
        }
        __syncthreads();
    }
}

// ===================================================================
// FALLBACK fused decoder (R6-lineage, known-passing) — ws too small.
// ===================================================================
__global__ __launch_bounds__(1024, 4) void dec_fused_kernel(
    const float* __restrict__ eps,
    const float* __restrict__ mu_W, const float* __restrict__ mu_b,
    const float* __restrict__ lv_W, const float* __restrict__ lv_b,
    const float* __restrict__ di_W, const float* __restrict__ di_b,
    const float* __restrict__ dec_Wih, const float* __restrict__ dec_Whh,
    const float* __restrict__ dec_bih, const float* __restrict__ dec_bhh,
    const float* __restrict__ out_W, const float* __restrict__ out_b,
    float* __restrict__ out)
{
    __shared__ _Float16 s_hb[2][16 * H_LD];
    __shared__ f16x4 s_zp[256 * ZP_LD];
    __shared__ __attribute__((aligned(16))) unsigned char s_outw[VOCAB * 512];
    __shared__ float s_hl[16 * 260];

    const int tid  = threadIdx.x;
    const int lane = tid & 63;
    const int wv   = tid >> 6;
    const int l15  = lane & 15;
    const int lgrp = lane >> 4;
    const int bbase = blockIdx.x * 16;
    const int col  = wv * 16 + l15;

    for (int i = tid; i < 16 * HDIM; i += 1024) {
        int m = i >> 8, c = i & 255;
        s_hl[m * 260 + c] = out[(size_t)(bbase + m) * LROW + c];
    }
    for (int idx = tid; idx < VOCAB * HDIM; idx += 1024) {
        int r = idx >> 8, k = idx & 255;
        _Float16 w = (_Float16)out_W[r * 256 + k];
        *(short*)(s_outw + r * 512 + ((2 * k) ^ ((r & 7) << 4))) = __builtin_bit_cast(short, w);
    }

    f16x8 Breg[3][8];
    #pragma unroll
    for (int g = 0; g < 3; ++g)
        #pragma unroll
        for (int ks = 0; ks < 8; ++ks) {
            const float* p = dec_Whh + (g * 256 + col) * HDIM + ks * 32 + lgrp * 8;
            float4 a = *(const float4*)p;
            float4 b = *(const float4*)(p + 4);
            f16x8 w = {(_Float16)a.x, (_Float16)a.y, (_Float16)a.z, (_Float16)a.w,
                       (_Float16)b.x, (_Float16)b.y, (_Float16)b.z, (_Float16)b.w};
            Breg[g][ks] = w;
        }
    __syncthreads();

    float zv;
    {
        const size_t MU_OFF = (size_t)BB * TT * VOCAB;
        const size_t LV_OFF = MU_OFF + (size_t)BB * LDIM;
        int m = tid >> 6, j = tid & 63;
        const float* mwr = mu_W + j * HDIM;
        const float* lwr = lv_W + j * HDIM;
        float am = mu_b[j], al = lv_b[j];
        #pragma unroll 4
        for (int k = 0; k < HDIM; ++k) { float hv = s_hl[m * 260 + k]; am += hv * mwr[k]; al += hv * lwr[k]; }
        size_t bo = (size_t)(bbase + m) * LDIM + j;
        out[MU_OFF + bo] = am;
        out[LV_OFF + bo] = al;
        zv = am + eps[bo] * __expf(0.5f * al);
    }
    __syncthreads();
    { int m = tid >> 6, j = tid & 63; s_hl[m * 260 + j] = zv; }
    __syncthreads();

    float th[4];
    {
        const int gc = tid & 255;
        const int gm = tid >> 8;
        float ah[4], ar[4], az[4], an[4];
        float dib = di_b[gc];
        float bir = dec_bih[gc], biz = dec_bih[gc + 256], bin_ = dec_bih[gc + 512];
        #pragma unroll
        for (int i = 0; i < 4; ++i) { ah[i] = dib; ar[i] = bir; az[i] = biz; an[i] = bin_; }
        const float* w0 = di_W + gc * LDIM;
        const float* w1 = dec_Wih + gc * LDIM;
        const float* w2 = dec_Wih + (gc + 256) * LDIM;
        const float* w3 = dec_Wih + (gc + 512) * LDIM;
        #pragma unroll 2
        for (int j = 0; j < LDIM; ++j) {
            float a0 = w0[j], a1 = w1[j], a2 = w2[j], a3 = w3[j];
            #pragma unroll
            for (int i = 0; i < 4; ++i) {
                float q = s_hl[(gm * 4 + i) * 260 + j];
                ah[i] += q * a0; ar[i] += q * a1; az[i] += q * a2; an[i] += q * a3;
            }
        }
        float bhr = dec_bhh[gc], bhz = dec_bhh[gc + 256];
        __syncthreads();
        #pragma unroll
        for (int i = 0; i < 4; ++i) {
            int r = gm * 4 + i;
            th[i] = tanh_f(ah[i]);
            s_hl[r * 260 + gc] = th[i];
            f16x4 q = {(_Float16)(ar[i] + bhr), (_Float16)(az[i] + bhz), (_Float16)an[i], (_Float16)0.f};
            s_zp[gc * ZP_LD + r] = q;
            s_hb[0][r * H_LD + gc] = (_Float16)th[i];
        }
    }
    __syncthreads();

    float hpr[4];
    #pragma unroll
    for (int j = 0; j < 4; ++j) hpr[j] = s_hl[(lgrp * 4 + j) * 260 + col];

    const float bhn = dec_bhh[512 + col];
    const int vcol = wv * 16 + l15;
    const int orow = (vcol < VOCAB) ? vcol : (VOCAB - 1);
    const float ob = (wv < 7 && vcol < VOCAB) ? out_b[vcol] : 0.0f;
    const f32x4 z4 = {0.f, 0.f, 0.f, 0.f};

    #pragma unroll 1
    for (int t = 0; t < TT; ++t) {
        const _Float16* rh = s_hb[t & 1];
        _Float16* wh = s_hb[(t + 1) & 1];

        f32x4 a0 = z4, a1 = z4, a2 = z4, aco = z4;
        #pragma unroll
        for (int ks = 0; ks < 8; ++ks) {
            f16x8 a = *(const f16x8*)(rh + l15 * H_LD + ks * 32 + lgrp * 8);
            a0 = __builtin_amdgcn_mfma_f32_16x16x32_f16(a, Breg[0][ks], a0, 0, 0, 0);
            a1 = __builtin_amdgcn_mfma_f32_16x16x32_f16(a, Breg[1][ks], a1, 0, 0, 0);
            a2 = __builtin_amdgcn_mfma_f32_16x16x32_f16(a, Breg[2][ks], a2, 0, 0, 0);
            if (wv < 7) {
                f16x8 wo = *(const f16x8*)(s_outw + orow * 512 + ((ks * 64 + lgrp * 16) ^ ((orow & 7) << 4)));
                aco = __builtin_amdgcn_mfma_f32_16x16x32_f16(a, wo, aco, 0, 0, 0);
            }
        }
        if (t > 0 && wv < 7 && vcol < VOCAB) {
            size_t base = (size_t)(bbase + lgrp * 4) * LROW + (size_t)(t - 1) * VOCAB + vcol;
            #pragma unroll
            for (int j = 0; j < 4; ++j) out[base + (size_t)j * LROW] = aco[j] + ob;
        }
        #pragma unroll
        for (int j = 0; j < 4; ++j) {
            const int row = lgrp * 4 + j;
            f16x4 q = s_zp[col * ZP_LD + lgrp * 4 + j];
            float rg = sigf(a0[j] + (float)q[0]);
            float zg = sigf(a1[j] + (float)q[1]);
            float n  = tanh_f((float)q[2] + rg * (a2[j] + bhn));
            float h  = n + zg * (hpr[j] - n);
            hpr[j] = h;
            wh[row * H_LD + col] = (_Float16)h;
        }
        barrier_lgkm();
    }

    if (wv < 7) {
        const _Float16* rh = s_hb[0];
        f32x4 aco = z4;
        #pragma unroll
        for (int ks = 0; ks < 8; ++ks) {
            f16x8 a  = *(const f16x8*)(rh + l15 * H_LD + ks * 32 + lgrp * 8);
            f16x8 wo = *(const f16x8*)(s_outw + orow * 512 + ((ks * 64 + lgrp * 16) ^ ((orow & 7) << 4)));
            aco = __builtin_amdgcn_mfma_f32_16x16x32_f16(a, wo, aco, 0, 0, 0);
        }
        if (vcol < VOCAB) {
            size_t base = (size_t)(bbase + lgrp * 4) * LROW + (size_t)(TT - 1) * VOCAB + vcol;
            #pragma unroll
            for (int j = 0; j < 4; ++j) out[base + (size_t)j * LROW] = aco[j] + ob;
        }
    }
}

extern "C" void kernel_launch(void* const* d_in, const int* in_sizes, int n_in,
                              void* d_out, int out_size, void* d_ws, size_t ws_size,
                              hipStream_t stream) {
    const int*   x       = (const int*)  d_in[0];
    const float* eps     = (const float*)d_in[1];
    const float* emb     = (const float*)d_in[2];
    const float* enc_Wih = (const float*)d_in[3];
    const float* enc_Whh = (const float*)d_in[4];
    const float* enc_bih = (const float*)d_in[5];
    const float* enc_bhh = (const float*)d_in[6];
    const float* mu_W    = (const float*)d_in[7];
    const float* mu_b    = (const float*)d_in[8];
    const float* lv_W    = (const float*)d_in[9];
    const float* lv_b    = (const float*)d_in[10];
    const float* di_W    = (const float*)d_in[11];
    const float* di_b    = (const float*)d_in[12];
    const float* dec_Wih = (const float*)d_in[13];
    const float* dec_Whh = (const float*)d_in[14];
    const float* dec_bih = (const float*)d_in[15];
    const float* dec_bhh = (const float*)d_in[16];
    const float* out_W   = (const float*)d_in[17];
    const float* out_b   = (const float*)d_in[18];
    float* out = (float*)d_out;

    _Float16* PT = (_Float16*)d_ws;                                  // [100][768] f16
    const size_t HOFFB = 153600;
    _Float16* Hbuf = (_Float16*)((char*)d_ws + HOFFB);               // [BB*TT][256] f16
    const size_t need = HOFFB + (size_t)BB * TT * 256 * sizeof(_Float16);

    pt_kernel<<<VOCAB, 256, 0, stream>>>(emb, enc_Wih, enc_bih, enc_bhh, PT);
    enc_kernel<<<BB / 16, 512, 0, stream>>>(x, PT, enc_Whh, enc_bhh, out);
    if (ws_size >= need) {
        dec_rnn_kernel<<<BB / 16, 512, 0, stream>>>(eps, mu_W, mu_b, lv_W, lv_b,
            di_W, di_b, dec_Wih, dec_Whh, dec_bih, dec_bhh, out, Hbuf);
        logits_kernel<<<(BB * TT / 16) / 32, 1024, 0, stream>>>(Hbuf, out_W, out_b, out);
    } else {
        dec_fused_kernel<<<BB / 16, 1024, 0, stream>>>(eps, mu_W, mu_b, lv_W, lv_b,
            di_W, di_b, dec_Wih, dec_Whh, dec_bih, dec_bhh, out_W, out_b, out);
    }
}

// Round 12
// 913.844 us; speedup vs baseline: 6.2673x; 1.0292x over previous
//
#include <hip/hip_runtime.h>
#include <hip/hip_bf16.h>

#define VOCAB 100
#define EDIM  128
#define HDIM  256
#define LDIM  64
#define G3    768
#define TT    128
#define BB    4096
#define LROW  (TT * VOCAB)
#define H_LD  264            // halfs per h-row (256 + 8 pad)
#define ZP_LD 17             // f16x4 units per zp col (16 rows + 1 pad)

typedef float    f32x4 __attribute__((ext_vector_type(4)));
typedef _Float16 f16x8 __attribute__((ext_vector_type(8)));
typedef _Float16 f16x4 __attribute__((ext_vector_type(4)));

__device__ __forceinline__ float sigf(float x) {
    return __builtin_amdgcn_rcpf(1.0f + __expf(-x));
}
__device__ __forceinline__ float tanh_f(float x) {
    return 2.0f * __builtin_amdgcn_rcpf(1.0f + __expf(-2.0f * x)) - 1.0f;
}
__device__ __forceinline__ void barrier_lgkm() {
    asm volatile("s_waitcnt lgkmcnt(0)\n\ts_barrier" ::: "memory");
}
__device__ __forceinline__ unsigned short h2b(_Float16 h) {
    return __builtin_bit_cast(unsigned short, h);
}

// plain B fragment (linear K) — for the 1024-thread encoder
__device__ __forceinline__ f16x8 ld_bfrag(const float* __restrict__ W, int outcol, int ks, int lgrp) {
    const float* p = W + outcol * HDIM + ks * 32 + lgrp * 8;
    float4 a = *(const float4*)p;
    float4 b = *(const float4*)(p + 4);
    f16x8 w = {(_Float16)a.x, (_Float16)a.y, (_Float16)a.z, (_Float16)a.w,
               (_Float16)b.x, (_Float16)b.y, (_Float16)b.z, (_Float16)b.w};
    return w;
}

// B fragment for the K-PERMUTED h layout (R3/R11-verified):
// physical k p -> logical k_log = (p&~31) | ((p&1)<<4) | ((p&31)>>1)
__device__ __forceinline__ f16x8 ld_bfragK(const float* __restrict__ W, int outcol, int ks, int lgrp) {
    const float* p = W + outcol * HDIM + ks * 32 + lgrp * 4;
    float4 f0 = *(const float4*)p;
    float4 f1 = *(const float4*)(p + 16);
    f16x8 w = {(_Float16)f0.x, (_Float16)f1.x, (_Float16)f0.y, (_Float16)f1.y,
               (_Float16)f0.z, (_Float16)f1.z, (_Float16)f0.w, (_Float16)f1.w};
    return w;
}

// ---------------- prep: PT2[v][g] = enc_Wih@emb[v] + enc_bih + (g<512 ? enc_bhh : 0), f16 ----------------
__global__ void pt_kernel(const float* __restrict__ emb, const float* __restrict__ Wih,
                          const float* __restrict__ bih, const float* __restrict__ bhh,
                          _Float16* __restrict__ PT) {
    int v = blockIdx.x;
    __shared__ float se[EDIM];
    for (int e = threadIdx.x; e < EDIM; e += blockDim.x) se[e] = emb[v * EDIM + e];
    __syncthreads();
    for (int g = threadIdx.x; g < G3; g += blockDim.x) {
        const float* wr = Wih + g * EDIM;
        float acc = bih[g] + (g < 512 ? bhh[g] : 0.0f);
        #pragma unroll 8
        for (int e = 0; e < EDIM; ++e) acc += se[e] * wr[e];
        PT[v * G3 + g] = (_Float16)acc;
    }
}

// ===================================================================
// ENCODER (R10-verified): 1024 thr / 16 waves, 16 rows/block. Wave owns
// 16 cols x 3 gates = 96 weight VGPRs (no spill). Gathers issued at
// step top; next-step token prefetched during gates.
// ===================================================================
__global__ __launch_bounds__(1024, 4) void enc_kernel(
    const int* __restrict__ x, const _Float16* __restrict__ PT2,
    const float* __restrict__ Whh, const float* __restrict__ bhh,
    float* __restrict__ out)
{
    __shared__ _Float16 s_h[2][16 * H_LD];
    __shared__ int s_tok[16 * TT];

    const int tid  = threadIdx.x;
    const int lane = tid & 63;
    const int wv   = tid >> 6;
    const int l15  = lane & 15;
    const int lgrp = lane >> 4;
    const int bbase = blockIdx.x * 16;
    const int col  = wv * 16 + l15;

    for (int i = tid; i < 16 * TT; i += 1024) s_tok[i] = x[bbase * TT + i];

    f16x8 Breg[3][8];
    #pragma unroll
    for (int g = 0; g < 3; ++g)
        #pragma unroll
        for (int ks = 0; ks < 8; ++ks)
            Breg[g][ks] = ld_bfrag(Whh, g * 256 + col, ks, lgrp);

    const float bhn = bhh[512 + col];
    float hst[4] = {0.f, 0.f, 0.f, 0.f};

    for (int i = tid; i < 16 * H_LD; i += 1024) s_h[0][i] = (_Float16)0.f;
    __syncthreads();

    int tokp[4];
    #pragma unroll
    for (int j = 0; j < 4; ++j) tokp[j] = s_tok[(lgrp * 4 + j) * TT];

    const f32x4 z4 = {0.f, 0.f, 0.f, 0.f};

    #pragma unroll 1
    for (int t = 0; t < TT; ++t) {
        const _Float16* rh = s_h[t & 1];
        _Float16* wh = s_h[(t + 1) & 1];

        // issue gate-input gathers FIRST: latency hides under the MFMA phase
        _Float16 pr[4], pz[4], pn[4];
        #pragma unroll
        for (int j = 0; j < 4; ++j) {
            const _Float16* p = PT2 + tokp[j] * G3 + col;
            pr[j] = p[0]; pz[j] = p[256]; pn[j] = p[512];
        }

        f32x4 a0 = z4, a1 = z4, a2 = z4;
        #pragma unroll
        for (int ks = 0; ks < 8; ++ks) {
            f16x8 a = *(const f16x8*)(rh + l15 * H_LD + ks * 32 + lgrp * 8);
            a0 = __builtin_amdgcn_mfma_f32_16x16x32_f16(a, Breg[0][ks], a0, 0, 0, 0);
            a1 = __builtin_amdgcn_mfma_f32_16x16x32_f16(a, Breg[1][ks], a1, 0, 0, 0);
            a2 = __builtin_amdgcn_mfma_f32_16x16x32_f16(a, Breg[2][ks], a2, 0, 0, 0);
        }

        // prefetch next-step tokens (LDS) while gates run
        if (t + 1 < TT) {
            #pragma unroll
            for (int j = 0; j < 4; ++j) tokp[j] = s_tok[(lgrp * 4 + j) * TT + t + 1];
        }

        #pragma unroll
        for (int j = 0; j < 4; ++j) {
            const int row = lgrp * 4 + j;
            float rg = sigf(a0[j] + (float)pr[j]);
            float zg = sigf(a1[j] + (float)pz[j]);
            float n  = tanh_f((float)pn[j] + rg * (a2[j] + bhn));
            float h  = n + zg * (hst[j] - n);
            hst[j] = h;
            wh[row * H_LD + col] = (_Float16)h;
            if (t == TT - 1) out[(size_t)(bbase + row) * LROW + col] = h;
        }
        barrier_lgkm();
    }
}

// ===================================================================
// DECODER RNN (R11-verified): 512 thr / 8 waves, 16 rows/block, Breg 192
// under the 256-reg cap (no spill). Streams h_t (K-permuted) to Hbuf.
// ===================================================================
__global__ __launch_bounds__(512, 2) void dec_rnn_kernel(
    const float* __restrict__ eps,
    const float* __restrict__ mu_W, const float* __restrict__ mu_b,
    const float* __restrict__ lv_W, const float* __restrict__ lv_b,
    const float* __restrict__ di_W, const float* __restrict__ di_b,
    const float* __restrict__ dec_Wih, const float* __restrict__ dec_Whh,
    const float* __restrict__ dec_bih, const float* __restrict__ dec_bhh,
    float* __restrict__ out, _Float16* __restrict__ Hbuf)
{
    __shared__ _Float16 s_hb[2][16 * H_LD];   // 16896 B
    __shared__ f16x4 s_zp[256 * ZP_LD];       // 34816 B {r+bhr, z+bhz, n, bhn}
    __shared__ float s_hl[16 * 260];          // 16640 B

    const int tid  = threadIdx.x;
    const int lane = tid & 63;
    const int wv   = tid >> 6;
    const int l15  = lane & 15;
    const int lgrp = lane >> 4;
    const int bbase = blockIdx.x * 16;
    const int colb = wv * 32 + l15;

    for (int i = tid; i < 16 * HDIM; i += 512) {
        int m = i >> 8, c = i & 255;
        s_hl[m * 260 + c] = out[(size_t)(bbase + m) * LROW + c];
    }

    f16x8 Breg[3][2][8];
    #pragma unroll
    for (int g = 0; g < 3; ++g)
        #pragma unroll
        for (int cg = 0; cg < 2; ++cg)
            #pragma unroll
            for (int ks = 0; ks < 8; ++ks)
                Breg[g][cg][ks] = ld_bfragK(dec_Whh, g * 256 + colb + cg * 16, ks, lgrp);
    __syncthreads();

    // ---- mu / logvar / z : 2 outputs per thread ----
    float z0 = 0.f, z1 = 0.f;
    {
        const size_t MU_OFF = (size_t)BB * TT * VOCAB;
        const size_t LV_OFF = MU_OFF + (size_t)BB * LDIM;
        #pragma unroll
        for (int oo = 0; oo < 2; ++oo) {
            int o = tid * 2 + oo;
            int m = o >> 6, j = o & 63;
            const float* mwr = mu_W + j * HDIM;
            const float* lwr = lv_W + j * HDIM;
            float am = mu_b[j], al = lv_b[j];
            #pragma unroll 4
            for (int k = 0; k < HDIM; ++k) { float hv = s_hl[m * 260 + k]; am += hv * mwr[k]; al += hv * lwr[k]; }
            size_t bo = (size_t)(bbase + m) * LDIM + j;
            out[MU_OFF + bo] = am;
            out[LV_OFF + bo] = al;
            float zv = am + eps[bo] * __expf(0.5f * al);
            if (oo == 0) z0 = zv; else z1 = zv;
        }
    }
    __syncthreads();                 // all h_last reads done
    {
        int o0 = tid * 2;
        s_hl[(o0 >> 6) * 260 + (o0 & 63)] = z0;
        int o1 = o0 + 1;
        s_hl[(o1 >> 6) * 260 + (o1 & 63)] = z1;
    }
    __syncthreads();                 // z staged (rows 0..15, cols 0..63)

    // ---- hidden = tanh(di_W z + di_b); zp = dec_Wih z + dec_bih (+bhh r,z; bhn in slot3) ----
    {
        const int gc = tid & 255;
        const int gm2 = tid >> 8;    // 0/1: row parity
        float ah[8], ar[8], az[8], an[8];
        float dib = di_b[gc];
        float bir = dec_bih[gc], biz = dec_bih[gc + 256], bin_ = dec_bih[gc + 512];
        #pragma unroll
        for (int i = 0; i < 8; ++i) { ah[i] = dib; ar[i] = bir; az[i] = biz; an[i] = bin_; }
        const float* w0 = di_W + gc * LDIM;
        const float* w1 = dec_Wih + gc * LDIM;
        const float* w2 = dec_Wih + (gc + 256) * LDIM;
        const float* w3 = dec_Wih + (gc + 512) * LDIM;
        #pragma unroll 2
        for (int j = 0; j < LDIM; ++j) {
            float a0 = w0[j], a1 = w1[j], a2 = w2[j], a3 = w3[j];
            #pragma unroll
            for (int i = 0; i < 8; ++i) {
                float q = s_hl[(gm2 + 2 * i) * 260 + j];
                ah[i] += q * a0; ar[i] += q * a1; az[i] += q * a2; an[i] += q * a3;
            }
        }
        float bhr = dec_bhh[gc], bhz = dec_bhh[gc + 256], bhn_c = dec_bhh[gc + 512];
        __syncthreads();             // z reads done before s_hl overwrite
        int pcol = (gc & ~31) | ((gc & 15) << 1) | ((gc >> 4) & 1);
        #pragma unroll
        for (int i = 0; i < 8; ++i) {
            int m = gm2 + 2 * i;
            float th = tanh_f(ah[i]);
            s_hl[m * 260 + gc] = th;
            f16x4 q = {(_Float16)(ar[i] + bhr), (_Float16)(az[i] + bhz), (_Float16)an[i], (_Float16)bhn_c};
            s_zp[gc * ZP_LD + m] = q;
            s_hb[0][m * H_LD + pcol] = (_Float16)th;
        }
    }
    __syncthreads();                 // th/zp/h0 staged

    float hpr[4][2];
    #pragma unroll
    for (int j = 0; j < 4; ++j) {
        hpr[j][0] = s_hl[(lgrp * 4 + j) * 260 + colb];
        hpr[j][1] = s_hl[(lgrp * 4 + j) * 260 + colb + 16];
    }

    const f32x4 z4 = {0.f, 0.f, 0.f, 0.f};
    const int crow = tid >> 5;       // 0..15
    const int cseg = tid & 31;       // 0..31 (16B chunks)
    _Float16* hb = Hbuf + ((size_t)(bbase + crow) * TT) * 256 + cseg * 8;
    const int lread = crow * H_LD + cseg * 8;

    #pragma unroll 1
    for (int t = 0; t < TT; ++t) {
        const _Float16* rh = s_hb[t & 1];
        _Float16* wh = s_hb[(t + 1) & 1];

        f32x4 acc[3][2];
        #pragma unroll
        for (int g = 0; g < 3; ++g) { acc[g][0] = z4; acc[g][1] = z4; }
        #pragma unroll
        for (int ks = 0; ks < 8; ++ks) {
            f16x8 a = *(const f16x8*)(rh + l15 * H_LD + ks * 32 + lgrp * 8);
            #pragma unroll
            for (int g = 0; g < 3; ++g) {
                acc[g][0] = __builtin_amdgcn_mfma_f32_16x16x32_f16(a, Breg[g][0][ks], acc[g][0], 0, 0, 0);
                acc[g][1] = __builtin_amdgcn_mfma_f32_16x16x32_f16(a, Breg[g][1][ks], acc[g][1], 0, 0, 0);
            }
        }
        #pragma unroll
        for (int j = 0; j < 4; ++j) {
            const int row = lgrp * 4 + j;
            f16x4 q0 = s_zp[colb * ZP_LD + row];
            f16x4 q1 = s_zp[(colb + 16) * ZP_LD + row];
            unsigned wpack = 0;
            #pragma unroll
            for (int cg = 0; cg < 2; ++cg) {
                f16x4 q = cg ? q1 : q0;
                float rg = sigf(acc[0][cg][j] + (float)q[0]);
                float zg = sigf(acc[1][cg][j] + (float)q[1]);
                float n  = tanh_f((float)q[2] + rg * (acc[2][cg][j] + (float)q[3]));
                float h  = n + zg * (hpr[j][cg] - n);
                hpr[j][cg] = h;
                wpack |= ((unsigned)h2b((_Float16)h)) << (16 * cg);
            }
            *(unsigned*)(wh + row * H_LD + wv * 32 + 2 * l15) = wpack;
        }
        barrier_lgkm();
        // stream h_{t+1} (logits row s=t), K-permuted: 8 KB coalesced/block-step
        *(f16x8*)hb = *(const f16x8*)(wh + lread);
        hb += 256;
    }
}

// ===================================================================
// LOGITS GEMM (R11-verified): out_W staged with matching K-permute;
// LDS-staged LINEAR copy-out (no RMW).
// ===================================================================
__global__ __launch_bounds__(1024, 4) void logits_kernel(
    const _Float16* __restrict__ Hbuf, const float* __restrict__ out_W,
    const float* __restrict__ out_b, float* __restrict__ out)
{
    __shared__ __attribute__((aligned(16))) unsigned char s_outw[VOCAB * 512]; // 51200 B
    __shared__ __attribute__((aligned(16))) float s_ls[256 * 108];             // 110592 B
    const int tid = threadIdx.x, lane = tid & 63, wv = tid >> 6;
    const int l15 = lane & 15, lgrp = lane >> 4;

    for (int idx = tid; idx < VOCAB * HDIM; idx += 1024) {
        int r = idx >> 8, kp = idx & 255;
        int kl = (kp & ~31) | ((kp & 1) << 4) | ((kp & 31) >> 1);   // K-permute
        _Float16 w = (_Float16)out_W[r * 256 + kl];
        *(short*)(s_outw + r * 512 + ((2 * kp) ^ ((r & 7) << 4))) = __builtin_bit_cast(short, w);
    }
    __syncthreads();

    float ob[7];
    #pragma unroll
    for (int vt = 0; vt < 7; ++vt) {
        int v = vt * 16 + l15;
        ob[vt] = (v < VOCAB) ? out_b[v] : 0.0f;
    }
    const f32x4 z4 = {0.f, 0.f, 0.f, 0.f};

    #pragma unroll 1
    for (int round = 0; round < 2; ++round) {
        size_t mt = (size_t)blockIdx.x * 32 + round * 16 + wv;   // 16-row tile index
        const _Float16* hrow = Hbuf + (mt * 16 + l15) * 256;
        f32x4 acc[7];
        #pragma unroll
        for (int vt = 0; vt < 7; ++vt) acc[vt] = z4;
        #pragma unroll
        for (int ks = 0; ks < 8; ++ks) {
            f16x8 a = *(const f16x8*)(hrow + ks * 32 + lgrp * 8);
            #pragma unroll
            for (int vt = 0; vt < 7; ++vt) {
                int orow = vt * 16 + l15; if (orow > VOCAB - 1) orow = VOCAB - 1;
                f16x8 wo = *(const f16x8*)(s_outw + orow * 512 + ((ks * 64 + lgrp * 16) ^ ((orow & 7) << 4)));
                acc[vt] = __builtin_amdgcn_mfma_f32_16x16x32_f16(a, wo, acc[vt], 0, 0, 0);
            }
        }
        #pragma unroll
        for (int vt = 0; vt < 7; ++vt) {
            int v = vt * 16 + l15;
            if (v < VOCAB) {
                #pragma unroll
                for (int j = 0; j < 4; ++j)
                    s_ls[(wv * 16 + lgrp * 4 + j) * 108 + v] = acc[vt][j] + ob[vt];
            }
        }
        __syncthreads();
        {
            size_t slabM0 = (size_t)blockIdx.x * 512 + round * 256;
            float* gbase = out + slabM0 * VOCAB;
            for (int c = tid; c < 6400; c += 1024) {
                int r = c / 25, cc = (c % 25) * 4;
                f32x4 vch = *(const f32x4*)(s_ls + r * 108 + cc);
                *(f32x4*)(gbase + (size_t)c * 4) = vch;
            }
        }
        __syncthreads();
    }
}

// ===================================================================
// FALLBACK fused decoder (known-passing) — used if ws too small.
// ===================================================================
__global__ __launch_bounds__(1024, 4) void dec_fused_kernel(
    const float* __restrict__ eps,
    const float* __restrict__ mu_W, const float* __restrict__ mu_b,
    const float* __restrict__ lv_W, const float* __restrict__ lv_b,
    const float* __restrict__ di_W, const float* __restrict__ di_b,
    const float* __restrict__ dec_Wih, const float* __restrict__ dec_Whh,
    const float* __restrict__ dec_bih, const float* __restrict__ dec_bhh,
    const float* __restrict__ out_W, const float* __restrict__ out_b,
    float* __restrict__ out)
{
    __shared__ _Float16 s_hb[2][16 * H_LD];
    __shared__ f16x4 s_zp[256 * ZP_LD];
    __shared__ __attribute__((aligned(16))) unsigned char s_outw[VOCAB * 512];
    __shared__ float s_hl[16 * 260];

    const int tid  = threadIdx.x;
    const int lane = tid & 63;
    const int wv   = tid >> 6;
    const int l15  = lane & 15;
    const int lgrp = lane >> 4;
    const int bbase = blockIdx.x * 16;
    const int col  = wv * 16 + l15;

    for (int i = tid; i < 16 * HDIM; i += 1024) {
        int m = i >> 8, c = i & 255;
        s_hl[m * 260 + c] = out[(size_t)(bbase + m) * LROW + c];
    }
    for (int idx = tid; idx < VOCAB * HDIM; idx += 1024) {
        int r = idx >> 8, k = idx & 255;
        _Float16 w = (_Float16)out_W[r * 256 + k];
        *(short*)(s_outw + r * 512 + ((2 * k) ^ ((r & 7) << 4))) = __builtin_bit_cast(short, w);
    }

    f16x8 Breg[3][8];
    #pragma unroll
    for (int g = 0; g < 3; ++g)
        #pragma unroll
        for (int ks = 0; ks < 8; ++ks)
            Breg[g][ks] = ld_bfrag(dec_Whh, g * 256 + col, ks, lgrp);
    __syncthreads();

    float zv;
    {
        const size_t MU_OFF = (size_t)BB * TT * VOCAB;
        const size_t LV_OFF = MU_OFF + (size_t)BB * LDIM;
        int m = tid >> 6, j = tid & 63;
        const float* mwr = mu_W + j * HDIM;
        const float* lwr = lv_W + j * HDIM;
        float am = mu_b[j], al = lv_b[j];
        #pragma unroll 4
        for (int k = 0; k < HDIM; ++k) { float hv = s_hl[m * 260 + k]; am += hv * mwr[k]; al += hv * lwr[k]; }
        size_t bo = (size_t)(bbase + m) * LDIM + j;
        out[MU_OFF + bo] = am;
        out[LV_OFF + bo] = al;
        zv = am + eps[bo] * __expf(0.5f * al);
    }
    __syncthreads();
    { int m = tid >> 6, j = tid & 63; s_hl[m * 260 + j] = zv; }
    __syncthreads();

    float th[4];
    {
        const int gc = tid & 255;
        const int gm = tid >> 8;
        float ah[4], ar[4], az[4], an[4];
        float dib = di_b[gc];
        float bir = dec_bih[gc], biz = dec_bih[gc + 256], bin_ = dec_bih[gc + 512];
        #pragma unroll
        for (int i = 0; i < 4; ++i) { ah[i] = dib; ar[i] = bir; az[i] = biz; an[i] = bin_; }
        const float* w0 = di_W + gc * LDIM;
        const float* w1 = dec_Wih + gc * LDIM;
        const float* w2 = dec_Wih + (gc + 256) * LDIM;
        const float* w3 = dec_Wih + (gc + 512) * LDIM;
        #pragma unroll 2
        for (int j = 0; j < LDIM; ++j) {
            float a0 = w0[j], a1 = w1[j], a2 = w2[j], a3 = w3[j];
            #pragma unroll
            for (int i = 0; i < 4; ++i) {
                float q = s_hl[(gm * 4 + i) * 260 + j];
                ah[i] += q * a0; ar[i] += q * a1; az[i] += q * a2; an[i] += q * a3;
            }
        }
        float bhr = dec_bhh[gc], bhz = dec_bhh[gc + 256];
        __syncthreads();
        #pragma unroll
        for (int i = 0; i < 4; ++i) {
            int r = gm * 4 + i;
            th[i] = tanh_f(ah[i]);
            s_hl[r * 260 + gc] = th[i];
            f16x4 q = {(_Float16)(ar[i] + bhr), (_Float16)(az[i] + bhz), (_Float16)an[i], (_Float16)0.f};
            s_zp[gc * ZP_LD + r] = q;
            s_hb[0][r * H_LD + gc] = (_Float16)th[i];
        }
    }
    __syncthreads();

    float hpr[4];
    #pragma unroll
    for (int j = 0; j < 4; ++j) hpr[j] = s_hl[(lgrp * 4 + j) * 260 + col];

    const float bhn = dec_bhh[512 + col];
    const int vcol = wv * 16 + l15;
    const int orow = (vcol < VOCAB) ? vcol : (VOCAB - 1);
    const float ob = (wv < 7 && vcol < VOCAB) ? out_b[vcol] : 0.0f;
    const f32x4 z4 = {0.f, 0.f, 0.f, 0.f};

    #pragma unroll 1
    for (int t = 0; t < TT; ++t) {
        const _Float16* rh = s_hb[t & 1];
        _Float16* wh = s_hb[(t + 1) & 1];

        f32x4 a0 = z4, a1 = z4, a2 = z4, aco = z4;
        #pragma unroll
        for (int ks = 0; ks < 8; ++ks) {
            f16x8 a = *(const f16x8*)(rh + l15 * H_LD + ks * 32 + lgrp * 8);
            a0 = __builtin_amdgcn_mfma_f32_16x16x32_f16(a, Breg[0][ks], a0, 0, 0, 0);
            a1 = __builtin_amdgcn_mfma_f32_16x16x32_f16(a, Breg[1][ks], a1, 0, 0, 0);
            a2 = __builtin_amdgcn_mfma_f32_16x16x32_f16(a, Breg[2][ks], a2, 0, 0, 0);
            if (wv < 7) {
                f16x8 wo = *(const f16x8*)(s_outw + orow * 512 + ((ks * 64 + lgrp * 16) ^ ((orow & 7) << 4)));
                aco = __builtin_amdgcn_mfma_f32_16x16x32_f16(a, wo, aco, 0, 0, 0);
            }
        }
        if (t > 0 && wv < 7 && vcol < VOCAB) {
            size_t base = (size_t)(bbase + lgrp * 4) * LROW + (size_t)(t - 1) * VOCAB + vcol;
            #pragma unroll
            for (int j = 0; j < 4; ++j) out[base + (size_t)j * LROW] = aco[j] + ob;
        }
        #pragma unroll
        for (int j = 0; j < 4; ++j) {
            const int row = lgrp * 4 + j;
            f16x4 q = s_zp[col * ZP_LD + lgrp * 4 + j];
            float rg = sigf(a0[j] + (float)q[0]);
            float zg = sigf(a1[j] + (float)q[1]);
            float n  = tanh_f((float)q[2] + rg * (a2[j] + bhn));
            float h  = n + zg * (hpr[j] - n);
            hpr[j] = h;
            wh[row * H_LD + col] = (_Float16)h;
        }
        barrier_lgkm();
    }

    if (wv < 7) {
        const _Float16* rh = s_hb[0];
        f32x4 aco = z4;
        #pragma unroll
        for (int ks = 0; ks < 8; ++ks) {
            f16x8 a  = *(const f16x8*)(rh + l15 * H_LD + ks * 32 + lgrp * 8);
            f16x8 wo = *(const f16x8*)(s_outw + orow * 512 + ((ks * 64 + lgrp * 16) ^ ((orow & 7) << 4)));
            aco = __builtin_amdgcn_mfma_f32_16x16x32_f16(a, wo, aco, 0, 0, 0);
        }
        if (vcol < VOCAB) {
            size_t base = (size_t)(bbase + lgrp * 4) * LROW + (size_t)(TT - 1) * VOCAB + vcol;
            #pragma unroll
            for (int j = 0; j < 4; ++j) out[base + (size_t)j * LROW] = aco[j] + ob;
        }
    }
}

extern "C" void kernel_launch(void* const* d_in, const int* in_sizes, int n_in,
                              void* d_out, int out_size, void* d_ws, size_t ws_size,
                              hipStream_t stream) {
    const int*   x       = (const int*)  d_in[0];
    const float* eps     = (const float*)d_in[1];
    const float* emb     = (const float*)d_in[2];
    const float* enc_Wih = (const float*)d_in[3];
    const float* enc_Whh = (const float*)d_in[4];
    const float* enc_bih = (const float*)d_in[5];
    const float* enc_bhh = (const float*)d_in[6];
    const float* mu_W    = (const float*)d_in[7];
    const float* mu_b    = (const float*)d_in[8];
    const float* lv_W    = (const float*)d_in[9];
    const float* lv_b    = (const float*)d_in[10];
    const float* di_W    = (const float*)d_in[11];
    const float* di_b    = (const float*)d_in[12];
    const float* dec_Wih = (const float*)d_in[13];
    const float* dec_Whh = (const float*)d_in[14];
    const float* dec_bih = (const float*)d_in[15];
    const float* dec_bhh = (const float*)d_in[16];
    const float* out_W   = (const float*)d_in[17];
    const float* out_b   = (const float*)d_in[18];
    float* out = (float*)d_out;

    _Float16* PT = (_Float16*)d_ws;                                  // [100][768] f16
    const size_t HOFFB = 153600;
    _Float16* Hbuf = (_Float16*)((char*)d_ws + HOFFB);               // [BB*TT][256] f16
    const size_t need = HOFFB + (size_t)BB * TT * 256 * sizeof(_Float16);

    pt_kernel<<<VOCAB, 256, 0, stream>>>(emb, enc_Wih, enc_bih, enc_bhh, PT);
    enc_kernel<<<BB / 16, 1024, 0, stream>>>(x, PT, enc_Whh, enc_bhh, out);
    if (ws_size >= need) {
        dec_rnn_kernel<<<BB / 16, 512, 0, stream>>>(eps, mu_W, mu_b, lv_W, lv_b,
            di_W, di_b, dec_Wih, dec_Whh, dec_bih, dec_bhh, out, Hbuf);
        logits_kernel<<<(BB * TT / 16) / 32, 1024, 0, stream>>>(Hbuf, out_W, out_b, out);
    } else {
        dec_fused_kernel<<<BB / 16, 1024, 0, stream>>>(eps, mu_W, mu_b, lv_W, lv_b,
            di_W, di_b, dec_Wih, dec_Whh, dec_bih, dec_bhh, out_W, out_b, out);
    }
}

// Round 13
// 860.389 us; speedup vs baseline: 6.6567x; 1.0621x over previous
//
#include <hip/hip_runtime.h>
#include <hip/hip_bf16.h>

#define VOCAB 100
#define EDIM  128
#define HDIM  256
#define LDIM  64
#define G3    768
#define TT    128
#define BB    4096
#define LROW  (TT * VOCAB)
#define H_LD  264            // halfs per h-row (256 + 8 pad)
#define ZP_LD 17             // f16x4 units per zp col (16 rows + 1 pad)

typedef float    f32x4 __attribute__((ext_vector_type(4)));
typedef _Float16 f16x8 __attribute__((ext_vector_type(8)));
typedef _Float16 f16x4 __attribute__((ext_vector_type(4)));

__device__ __forceinline__ float sigf(float x) {
    return __builtin_amdgcn_rcpf(1.0f + __expf(-x));
}
__device__ __forceinline__ float tanh_f(float x) {
    return 2.0f * __builtin_amdgcn_rcpf(1.0f + __expf(-2.0f * x)) - 1.0f;
}
__device__ __forceinline__ void barrier_lgkm() {
    asm volatile("s_waitcnt lgkmcnt(0)\n\ts_barrier" ::: "memory");
}

// plain B fragment (linear K)
__device__ __forceinline__ f16x8 ld_bfrag(const float* __restrict__ W, int outcol, int ks, int lgrp) {
    const float* p = W + outcol * HDIM + ks * 32 + lgrp * 8;
    float4 a = *(const float4*)p;
    float4 b = *(const float4*)(p + 4);
    f16x8 w = {(_Float16)a.x, (_Float16)a.y, (_Float16)a.z, (_Float16)a.w,
               (_Float16)b.x, (_Float16)b.y, (_Float16)b.z, (_Float16)b.w};
    return w;
}

// ---------------- prep: PT2[v][g] = enc_Wih@emb[v] + enc_bih + (g<512 ? enc_bhh : 0), f16 ----------------
__global__ void pt_kernel(const float* __restrict__ emb, const float* __restrict__ Wih,
                          const float* __restrict__ bih, const float* __restrict__ bhh,
                          _Float16* __restrict__ PT) {
    int v = blockIdx.x;
    __shared__ float se[EDIM];
    for (int e = threadIdx.x; e < EDIM; e += blockDim.x) se[e] = emb[v * EDIM + e];
    __syncthreads();
    for (int g = threadIdx.x; g < G3; g += blockDim.x) {
        const float* wr = Wih + g * EDIM;
        float acc = bih[g] + (g < 512 ? bhh[g] : 0.0f);
        #pragma unroll 8
        for (int e = 0; e < EDIM; ++e) acc += se[e] * wr[e];
        PT[v * G3 + g] = (_Float16)acc;
    }
}

// ===================================================================
// ENCODER (R10/R12-verified): 1024 thr / 16 waves, 16 rows/block.
// ===================================================================
__global__ __launch_bounds__(1024, 4) void enc_kernel(
    const int* __restrict__ x, const _Float16* __restrict__ PT2,
    const float* __restrict__ Whh, const float* __restrict__ bhh,
    float* __restrict__ out)
{
    __shared__ _Float16 s_h[2][16 * H_LD];
    __shared__ int s_tok[16 * TT];

    const int tid  = threadIdx.x;
    const int lane = tid & 63;
    const int wv   = tid >> 6;
    const int l15  = lane & 15;
    const int lgrp = lane >> 4;
    const int bbase = blockIdx.x * 16;
    const int col  = wv * 16 + l15;

    for (int i = tid; i < 16 * TT; i += 1024) s_tok[i] = x[bbase * TT + i];

    f16x8 Breg[3][8];
    #pragma unroll
    for (int g = 0; g < 3; ++g)
        #pragma unroll
        for (int ks = 0; ks < 8; ++ks)
            Breg[g][ks] = ld_bfrag(Whh, g * 256 + col, ks, lgrp);

    const float bhn = bhh[512 + col];
    float hst[4] = {0.f, 0.f, 0.f, 0.f};

    for (int i = tid; i < 16 * H_LD; i += 1024) s_h[0][i] = (_Float16)0.f;
    __syncthreads();

    int tokp[4];
    #pragma unroll
    for (int j = 0; j < 4; ++j) tokp[j] = s_tok[(lgrp * 4 + j) * TT];

    const f32x4 z4 = {0.f, 0.f, 0.f, 0.f};

    #pragma unroll 1
    for (int t = 0; t < TT; ++t) {
        const _Float16* rh = s_h[t & 1];
        _Float16* wh = s_h[(t + 1) & 1];

        _Float16 pr[4], pz[4], pn[4];
        #pragma unroll
        for (int j = 0; j < 4; ++j) {
            const _Float16* p = PT2 + tokp[j] * G3 + col;
            pr[j] = p[0]; pz[j] = p[256]; pn[j] = p[512];
        }

        f32x4 a0 = z4, a1 = z4, a2 = z4;
        #pragma unroll
        for (int ks = 0; ks < 8; ++ks) {
            f16x8 a = *(const f16x8*)(rh + l15 * H_LD + ks * 32 + lgrp * 8);
            a0 = __builtin_amdgcn_mfma_f32_16x16x32_f16(a, Breg[0][ks], a0, 0, 0, 0);
            a1 = __builtin_amdgcn_mfma_f32_16x16x32_f16(a, Breg[1][ks], a1, 0, 0, 0);
            a2 = __builtin_amdgcn_mfma_f32_16x16x32_f16(a, Breg[2][ks], a2, 0, 0, 0);
        }

        if (t + 1 < TT) {
            #pragma unroll
            for (int j = 0; j < 4; ++j) tokp[j] = s_tok[(lgrp * 4 + j) * TT + t + 1];
        }

        #pragma unroll
        for (int j = 0; j < 4; ++j) {
            const int row = lgrp * 4 + j;
            float rg = sigf(a0[j] + (float)pr[j]);
            float zg = sigf(a1[j] + (float)pz[j]);
            float n  = tanh_f((float)pn[j] + rg * (a2[j] + bhn));
            float h  = n + zg * (hst[j] - n);
            hst[j] = h;
            wh[row * H_LD + col] = (_Float16)h;
            if (t == TT - 1) out[(size_t)(bbase + row) * LROW + col] = h;
        }
        barrier_lgkm();
    }
}

// ===================================================================
// MID: standalone dec prologue (R12-verified math). Computes mu/lv -> out,
// z -> hidden h0 (f32) and zq = {r+bhr, z+bhz, n, bhn} (f16x4) -> ws.
// ===================================================================
__global__ __launch_bounds__(512, 2) void mid_kernel(
    const float* __restrict__ eps,
    const float* __restrict__ mu_W, const float* __restrict__ mu_b,
    const float* __restrict__ lv_W, const float* __restrict__ lv_b,
    const float* __restrict__ di_W, const float* __restrict__ di_b,
    const float* __restrict__ dec_Wih, const float* __restrict__ dec_bih,
    const float* __restrict__ dec_bhh,
    float* __restrict__ out, f16x4* __restrict__ zq_g, float* __restrict__ h0_g)
{
    __shared__ float s_hl[16 * 260];          // 16640 B

    const int tid  = threadIdx.x;
    const int bbase = blockIdx.x * 16;

    for (int i = tid; i < 16 * HDIM; i += 512) {
        int m = i >> 8, c = i & 255;
        s_hl[m * 260 + c] = out[(size_t)(bbase + m) * LROW + c];
    }
    __syncthreads();

    // ---- mu / logvar / z : 2 outputs per thread ----
    float z0 = 0.f, z1 = 0.f;
    {
        const size_t MU_OFF = (size_t)BB * TT * VOCAB;
        const size_t LV_OFF = MU_OFF + (size_t)BB * LDIM;
        #pragma unroll
        for (int oo = 0; oo < 2; ++oo) {
            int o = tid * 2 + oo;
            int m = o >> 6, j = o & 63;
            const float* mwr = mu_W + j * HDIM;
            const float* lwr = lv_W + j * HDIM;
            float am = mu_b[j], al = lv_b[j];
            #pragma unroll 4
            for (int k = 0; k < HDIM; ++k) { float hv = s_hl[m * 260 + k]; am += hv * mwr[k]; al += hv * lwr[k]; }
            size_t bo = (size_t)(bbase + m) * LDIM + j;
            out[MU_OFF + bo] = am;
            out[LV_OFF + bo] = al;
            float zv = am + eps[bo] * __expf(0.5f * al);
            if (oo == 0) z0 = zv; else z1 = zv;
        }
    }
    __syncthreads();                 // all h_last reads done
    {
        int o0 = tid * 2;
        s_hl[(o0 >> 6) * 260 + (o0 & 63)] = z0;
        int o1 = o0 + 1;
        s_hl[(o1 >> 6) * 260 + (o1 & 63)] = z1;
    }
    __syncthreads();                 // z staged (rows 0..15, cols 0..63)

    {
        const int gc = tid & 255;
        const int gm2 = tid >> 8;    // 0/1: row parity
        float ah[8], ar[8], az[8], an[8];
        float dib = di_b[gc];
        float bir = dec_bih[gc], biz = dec_bih[gc + 256], bin_ = dec_bih[gc + 512];
        #pragma unroll
        for (int i = 0; i < 8; ++i) { ah[i] = dib; ar[i] = bir; az[i] = biz; an[i] = bin_; }
        const float* w0 = di_W + gc * LDIM;
        const float* w1 = dec_Wih + gc * LDIM;
        const float* w2 = dec_Wih + (gc + 256) * LDIM;
        const float* w3 = dec_Wih + (gc + 512) * LDIM;
        #pragma unroll 2
        for (int j = 0; j < LDIM; ++j) {
            float a0 = w0[j], a1 = w1[j], a2 = w2[j], a3 = w3[j];
            #pragma unroll
            for (int i = 0; i < 8; ++i) {
                float q = s_hl[(gm2 + 2 * i) * 260 + j];
                ah[i] += q * a0; ar[i] += q * a1; az[i] += q * a2; an[i] += q * a3;
            }
        }
        float bhr = dec_bhh[gc], bhz = dec_bhh[gc + 256], bhn_c = dec_bhh[gc + 512];
        #pragma unroll
        for (int i = 0; i < 8; ++i) {
            int m = gm2 + 2 * i;
            float th = tanh_f(ah[i]);
            h0_g[(size_t)(bbase + m) * 256 + gc] = th;
            f16x4 q = {(_Float16)(ar[i] + bhr), (_Float16)(az[i] + bhz), (_Float16)an[i], (_Float16)bhn_c};
            zq_g[(size_t)(bbase + m) * 256 + gc] = q;
        }
    }
}

// ===================================================================
// DECODER RNN: enc-identical geometry (1024 thr / 16 waves, Breg 96).
// Pure GRU loop; zq from LDS; streams h_t (linear) to Hbuf.
// ===================================================================
__global__ __launch_bounds__(1024, 4) void dec_rnn_kernel(
    const float* __restrict__ dec_Whh,
    const f16x4* __restrict__ zq_g, const float* __restrict__ h0_g,
    _Float16* __restrict__ Hbuf)
{
    __shared__ _Float16 s_hb[2][16 * H_LD];   // 16896 B
    __shared__ f16x4 s_zq[256 * ZP_LD];       // 34816 B

    const int tid  = threadIdx.x;
    const int lane = tid & 63;
    const int wv   = tid >> 6;
    const int l15  = lane & 15;
    const int lgrp = lane >> 4;
    const int bbase = blockIdx.x * 16;
    const int col  = wv * 16 + l15;

    // stage h0 (f16) and zq into LDS
    for (int i = tid; i < 16 * HDIM; i += 1024) {
        int row = i >> 8, c = i & 255;
        float hv = h0_g[(size_t)(bbase + row) * 256 + c];
        s_hb[0][row * H_LD + c] = (_Float16)hv;
        s_zq[c * ZP_LD + row] = zq_g[(size_t)(bbase + row) * 256 + c];
    }

    f16x8 Breg[3][8];
    #pragma unroll
    for (int g = 0; g < 3; ++g)
        #pragma unroll
        for (int ks = 0; ks < 8; ++ks)
            Breg[g][ks] = ld_bfrag(dec_Whh, g * 256 + col, ks, lgrp);

    float hst[4];
    #pragma unroll
    for (int j = 0; j < 4; ++j)
        hst[j] = h0_g[(size_t)(bbase + lgrp * 4 + j) * 256 + col];
    __syncthreads();

    const f32x4 z4 = {0.f, 0.f, 0.f, 0.f};
    const int crow = tid >> 6;       // 0..15
    const int cseg = lane;           // 0..63 (8B chunks)
    _Float16* hb = Hbuf + ((size_t)(bbase + crow) * TT) * 256 + cseg * 4;
    const int lread = crow * H_LD + cseg * 4;

    #pragma unroll 1
    for (int t = 0; t < TT; ++t) {
        const _Float16* rh = s_hb[t & 1];
        _Float16* wh = s_hb[(t + 1) & 1];

        f32x4 a0 = z4, a1 = z4, a2 = z4;
        #pragma unroll
        for (int ks = 0; ks < 8; ++ks) {
            f16x8 a = *(const f16x8*)(rh + l15 * H_LD + ks * 32 + lgrp * 8);
            a0 = __builtin_amdgcn_mfma_f32_16x16x32_f16(a, Breg[0][ks], a0, 0, 0, 0);
            a1 = __builtin_amdgcn_mfma_f32_16x16x32_f16(a, Breg[1][ks], a1, 0, 0, 0);
            a2 = __builtin_amdgcn_mfma_f32_16x16x32_f16(a, Breg[2][ks], a2, 0, 0, 0);
        }
        #pragma unroll
        for (int j = 0; j < 4; ++j) {
            const int row = lgrp * 4 + j;
            f16x4 q = s_zq[col * ZP_LD + row];
            float rg = sigf(a0[j] + (float)q[0]);
            float zg = sigf(a1[j] + (float)q[1]);
            float n  = tanh_f((float)q[2] + rg * (a2[j] + (float)q[3]));
            float h  = n + zg * (hst[j] - n);
            hst[j] = h;
            wh[row * H_LD + col] = (_Float16)h;
        }
        barrier_lgkm();
        // stream h_{t+1} (logits row s=t): 8 KB coalesced, stays in vmcnt flight
        *(f16x4*)hb = *(const f16x4*)(wh + lread);
        hb += 256;
    }
}

// ===================================================================
// LOGITS GEMM (R10-verified, linear K): LDS-staged LINEAR copy-out.
// ===================================================================
__global__ __launch_bounds__(1024, 4) void logits_kernel(
    const _Float16* __restrict__ Hbuf, const float* __restrict__ out_W,
    const float* __restrict__ out_b, float* __restrict__ out)
{
    __shared__ __attribute__((aligned(16))) unsigned char s_outw[VOCAB * 512]; // 51200 B
    __shared__ __attribute__((aligned(16))) float s_ls[256 * 108];             // 110592 B
    const int tid = threadIdx.x, lane = tid & 63, wv = tid >> 6;
    const int l15 = lane & 15, lgrp = lane >> 4;

    for (int idx = tid; idx < VOCAB * HDIM; idx += 1024) {
        int r = idx >> 8, k = idx & 255;
        _Float16 w = (_Float16)out_W[r * 256 + k];
        *(short*)(s_outw + r * 512 + ((2 * k) ^ ((r & 7) << 4))) = __builtin_bit_cast(short, w);
    }
    __syncthreads();

    float ob[7];
    #pragma unroll
    for (int vt = 0; vt < 7; ++vt) {
        int v = vt * 16 + l15;
        ob[vt] = (v < VOCAB) ? out_b[v] : 0.0f;
    }
    const f32x4 z4 = {0.f, 0.f, 0.f, 0.f};

    #pragma unroll 1
    for (int round = 0; round < 2; ++round) {
        size_t mt = (size_t)blockIdx.x * 32 + round * 16 + wv;   // 16-row tile index
        const _Float16* hrow = Hbuf + (mt * 16 + l15) * 256;
        f32x4 acc[7];
        #pragma unroll
        for (int vt = 0; vt < 7; ++vt) acc[vt] = z4;
        #pragma unroll
        for (int ks = 0; ks < 8; ++ks) {
            f16x8 a = *(const f16x8*)(hrow + ks * 32 + lgrp * 8);
            #pragma unroll
            for (int vt = 0; vt < 7; ++vt) {
                int orow = vt * 16 + l15; if (orow > VOCAB - 1) orow = VOCAB - 1;
                f16x8 wo = *(const f16x8*)(s_outw + orow * 512 + ((ks * 64 + lgrp * 16) ^ ((orow & 7) << 4)));
                acc[vt] = __builtin_amdgcn_mfma_f32_16x16x32_f16(a, wo, acc[vt], 0, 0, 0);
            }
        }
        #pragma unroll
        for (int vt = 0; vt < 7; ++vt) {
            int v = vt * 16 + l15;
            if (v < VOCAB) {
                #pragma unroll
                for (int j = 0; j < 4; ++j)
                    s_ls[(wv * 16 + lgrp * 4 + j) * 108 + v] = acc[vt][j] + ob[vt];
            }
        }
        __syncthreads();
        {
            size_t slabM0 = (size_t)blockIdx.x * 512 + round * 256;
            float* gbase = out + slabM0 * VOCAB;
            for (int c = tid; c < 6400; c += 1024) {
                int r = c / 25, cc = (c % 25) * 4;
                f32x4 vch = *(const f32x4*)(s_ls + r * 108 + cc);
                *(f32x4*)(gbase + (size_t)c * 4) = vch;
            }
        }
        __syncthreads();
    }
}

// ===================================================================
// FALLBACK fused decoder (known-passing) — used if ws too small.
// ===================================================================
__global__ __launch_bounds__(1024, 4) void dec_fused_kernel(
    const float* __restrict__ eps,
    const float* __restrict__ mu_W, const float* __restrict__ mu_b,
    const float* __restrict__ lv_W, const float* __restrict__ lv_b,
    const float* __restrict__ di_W, const float* __restrict__ di_b,
    const float* __restrict__ dec_Wih, const float* __restrict__ dec_Whh,
    const float* __restrict__ dec_bih, const float* __restrict__ dec_bhh,
    const float* __restrict__ out_W, const float* __restrict__ out_b,
    float* __restrict__ out)
{
    __shared__ _Float16 s_hb[2][16 * H_LD];
    __shared__ f16x4 s_zp[256 * ZP_LD];
    __shared__ __attribute__((aligned(16))) unsigned char s_outw[VOCAB * 512];
    __shared__ float s_hl[16 * 260];

    const int tid  = threadIdx.x;
    const int lane = tid & 63;
    const int wv   = tid >> 6;
    const int l15  = lane & 15;
    const int lgrp = lane >> 4;
    const int bbase = blockIdx.x * 16;
    const int col  = wv * 16 + l15;

    for (int i = tid; i < 16 * HDIM; i += 1024) {
        int m = i >> 8, c = i & 255;
        s_hl[m * 260 + c] = out[(size_t)(bbase + m) * LROW + c];
    }
    for (int idx = tid; idx < VOCAB * HDIM; idx += 1024) {
        int r = idx >> 8, k = idx & 255;
        _Float16 w = (_Float16)out_W[r * 256 + k];
        *(short*)(s_outw + r * 512 + ((2 * k) ^ ((r & 7) << 4))) = __builtin_bit_cast(short, w);
    }

    f16x8 Breg[3][8];
    #pragma unroll
    for (int g = 0; g < 3; ++g)
        #pragma unroll
        for (int ks = 0; ks < 8; ++ks)
            Breg[g][ks] = ld_bfrag(dec_Whh, g * 256 + col, ks, lgrp);
    __syncthreads();

    float zv;
    {
        const size_t MU_OFF = (size_t)BB * TT * VOCAB;
        const size_t LV_OFF = MU_OFF + (size_t)BB * LDIM;
        int m = tid >> 6, j = tid & 63;
        const float* mwr = mu_W + j * HDIM;
        const float* lwr = lv_W + j * HDIM;
        float am = mu_b[j], al = lv_b[j];
        #pragma unroll 4
        for (int k = 0; k < HDIM; ++k) { float hv = s_hl[m * 260 + k]; am += hv * mwr[k]; al += hv * lwr[k]; }
        size_t bo = (size_t)(bbase + m) * LDIM + j;
        out[MU_OFF + bo] = am;
        out[LV_OFF + bo] = al;
        zv = am + eps[bo] * __expf(0.5f * al);
    }
    __syncthreads();
    { int m = tid >> 6, j = tid & 63; s_hl[m * 260 + j] = zv; }
    __syncthreads();

    float th[4];
    {
        const int gc = tid & 255;
        const int gm = tid >> 8;
        float ah[4], ar[4], az[4], an[4];
        float dib = di_b[gc];
        float bir = dec_bih[gc], biz = dec_bih[gc + 256], bin_ = dec_bih[gc + 512];
        #pragma unroll
        for (int i = 0; i < 4; ++i) { ah[i] = dib; ar[i] = bir; az[i] = biz; an[i] = bin_; }
        const float* w0 = di_W + gc * LDIM;
        const float* w1 = dec_Wih + gc * LDIM;
        const float* w2 = dec_Wih + (gc + 256) * LDIM;
        const float* w3 = dec_Wih + (gc + 512) * LDIM;
        #pragma unroll 2
        for (int j = 0; j < LDIM; ++j) {
            float a0 = w0[j], a1 = w1[j], a2 = w2[j], a3 = w3[j];
            #pragma unroll
            for (int i = 0; i < 4; ++i) {
                float q = s_hl[(gm * 4 + i) * 260 + j];
                ah[i] += q * a0; ar[i] += q * a1; az[i] += q * a2; an[i] += q * a3;
            }
        }
        float bhr = dec_bhh[gc], bhz = dec_bhh[gc + 256];
        __syncthreads();
        #pragma unroll
        for (int i = 0; i < 4; ++i) {
            int r = gm * 4 + i;
            th[i] = tanh_f(ah[i]);
            s_hl[r * 260 + gc] = th[i];
            f16x4 q = {(_Float16)(ar[i] + bhr), (_Float16)(az[i] + bhz), (_Float16)an[i], (_Float16)0.f};
            s_zp[gc * ZP_LD + r] = q;
            s_hb[0][r * H_LD + gc] = (_Float16)th[i];
        }
    }
    __syncthreads();

    float hpr[4];
    #pragma unroll
    for (int j = 0; j < 4; ++j) hpr[j] = s_hl[(lgrp * 4 + j) * 260 + col];

    const float bhn = dec_bhh[512 + col];
    const int vcol = wv * 16 + l15;
    const int orow = (vcol < VOCAB) ? vcol : (VOCAB - 1);
    const float ob = (wv < 7 && vcol < VOCAB) ? out_b[vcol] : 0.0f;
    const f32x4 z4 = {0.f, 0.f, 0.f, 0.f};

    #pragma unroll 1
    for (int t = 0; t < TT; ++t) {
        const _Float16* rh = s_hb[t & 1];
        _Float16* wh = s_hb[(t + 1) & 1];

        f32x4 a0 = z4, a1 = z4, a2 = z4, aco = z4;
        #pragma unroll
        for (int ks = 0; ks < 8; ++ks) {
            f16x8 a = *(const f16x8*)(rh + l15 * H_LD + ks * 32 + lgrp * 8);
            a0 = __builtin_amdgcn_mfma_f32_16x16x32_f16(a, Breg[0][ks], a0, 0, 0, 0);
            a1 = __builtin_amdgcn_mfma_f32_16x16x32_f16(a, Breg[1][ks], a1, 0, 0, 0);
            a2 = __builtin_amdgcn_mfma_f32_16x16x32_f16(a, Breg[2][ks], a2, 0, 0, 0);
            if (wv < 7) {
                f16x8 wo = *(const f16x8*)(s_outw + orow * 512 + ((ks * 64 + lgrp * 16) ^ ((orow & 7) << 4)));
                aco = __builtin_amdgcn_mfma_f32_16x16x32_f16(a, wo, aco, 0, 0, 0);
            }
        }
        if (t > 0 && wv < 7 && vcol < VOCAB) {
            size_t base = (size_t)(bbase + lgrp * 4) * LROW + (size_t)(t - 1) * VOCAB + vcol;
            #pragma unroll
            for (int j = 0; j < 4; ++j) out[base + (size_t)j * LROW] = aco[j] + ob;
        }
        #pragma unroll
        for (int j = 0; j < 4; ++j) {
            const int row = lgrp * 4 + j;
            f16x4 q = s_zp[col * ZP_LD + lgrp * 4 + j];
            float rg = sigf(a0[j] + (float)q[0]);
            float zg = sigf(a1[j] + (float)q[1]);
            float n  = tanh_f((float)q[2] + rg * (a2[j] + bhn));
            float h  = n + zg * (hpr[j] - n);
            hpr[j] = h;
            wh[row * H_LD + col] = (_Float16)h;
        }
        barrier_lgkm();
    }

    if (wv < 7) {
        const _Float16* rh = s_hb[0];
        f32x4 aco = z4;
        #pragma unroll
        for (int ks = 0; ks < 8; ++ks) {
            f16x8 a  = *(const f16x8*)(rh + l15 * H_LD + ks * 32 + lgrp * 8);
            f16x8 wo = *(const f16x8*)(s_outw + orow * 512 + ((ks * 64 + lgrp * 16) ^ ((orow & 7) << 4)));
            aco = __builtin_amdgcn_mfma_f32_16x16x32_f16(a, wo, aco, 0, 0, 0);
        }
        if (vcol < VOCAB) {
            size_t base = (size_t)(bbase + lgrp * 4) * LROW + (size_t)(TT - 1) * VOCAB + vcol;
            #pragma unroll
            for (int j = 0; j < 4; ++j) out[base + (size_t)j * LROW] = aco[j] + ob;
        }
    }
}

extern "C" void kernel_launch(void* const* d_in, const int* in_sizes, int n_in,
                              void* d_out, int out_size, void* d_ws, size_t ws_size,
                              hipStream_t stream) {
    const int*   x       = (const int*)  d_in[0];
    const float* eps     = (const float*)d_in[1];
    const float* emb     = (const float*)d_in[2];
    const float* enc_Wih = (const float*)d_in[3];
    const float* enc_Whh = (const float*)d_in[4];
    const float* enc_bih = (const float*)d_in[5];
    const float* enc_bhh = (const float*)d_in[6];
    const float* mu_W    = (const float*)d_in[7];
    const float* mu_b    = (const float*)d_in[8];
    const float* lv_W    = (const float*)d_in[9];
    const float* lv_b    = (const float*)d_in[10];
    const float* di_W    = (const float*)d_in[11];
    const float* di_b    = (const float*)d_in[12];
    const float* dec_Wih = (const float*)d_in[13];
    const float* dec_Whh = (const float*)d_in[14];
    const float* dec_bih = (const float*)d_in[15];
    const float* dec_bhh = (const float*)d_in[16];
    const float* out_W   = (const float*)d_in[17];
    const float* out_b   = (const float*)d_in[18];
    float* out = (float*)d_out;

    // ws layout: PT | zq | h0 | Hbuf
    _Float16* PT = (_Float16*)d_ws;                                  // 153600 B
    const size_t ZQ_OFF = 153600;
    const size_t H0_OFF = ZQ_OFF + (size_t)BB * 256 * 8;             // zq: 8 MB
    const size_t HB_OFF = H0_OFF + (size_t)BB * 256 * 4;             // h0: 4 MB
    f16x4*    zq_g = (f16x4*)((char*)d_ws + ZQ_OFF);
    float*    h0_g = (float*)((char*)d_ws + H0_OFF);
    _Float16* Hbuf = (_Float16*)((char*)d_ws + HB_OFF);              // 268.4 MB
    const size_t need = HB_OFF + (size_t)BB * TT * 256 * sizeof(_Float16);

    pt_kernel<<<VOCAB, 256, 0, stream>>>(emb, enc_Wih, enc_bih, enc_bhh, PT);
    enc_kernel<<<BB / 16, 1024, 0, stream>>>(x, PT, enc_Whh, enc_bhh, out);
    if (ws_size >= need) {
        mid_kernel<<<BB / 16, 512, 0, stream>>>(eps, mu_W, mu_b, lv_W, lv_b,
            di_W, di_b, dec_Wih, dec_bih, dec_bhh, out, zq_g, h0_g);
        dec_rnn_kernel<<<BB / 16, 1024, 0, stream>>>(dec_Whh, zq_g, h0_g, Hbuf);
        logits_kernel<<<(BB * TT / 16) / 32, 1024, 0, stream>>>(Hbuf, out_W, out_b, out);
    } else {
        dec_fused_kernel<<<BB / 16, 1024, 0, stream>>>(eps, mu_W, mu_b, lv_W, lv_b,
            di_W, di_b, dec_Wih, dec_Whh, dec_bih, dec_bhh, out_W, out_b, out);
    }
}

// Round 14
// 746.438 us; speedup vs baseline: 7.6729x; 1.1527x over previous
//
#include <hip/hip_runtime.h>
#include <hip/hip_bf16.h>

#define VOCAB 100
#define EDIM  128
#define HDIM  256
#define LDIM  64
#define G3    768
#define TT    128
#define BB    4096
#define LROW  (TT * VOCAB)
#define H_LD  264            // halfs per h-row (256 + 8 pad)
#define ZP_LD 17             // f16x4 units per zp col (16 rows + 1 pad)

typedef float    f32x4 __attribute__((ext_vector_type(4)));
typedef _Float16 f16x8 __attribute__((ext_vector_type(8)));
typedef _Float16 f16x4 __attribute__((ext_vector_type(4)));

__device__ __forceinline__ float sigf(float x) {
    return __builtin_amdgcn_rcpf(1.0f + __expf(-x));
}
__device__ __forceinline__ float tanh_f(float x) {
    return 2.0f * __builtin_amdgcn_rcpf(1.0f + __expf(-2.0f * x)) - 1.0f;
}
__device__ __forceinline__ void barrier_lgkm() {
    asm volatile("s_waitcnt lgkmcnt(0)\n\ts_barrier" ::: "memory");
}

// plain B fragment (linear K)
__device__ __forceinline__ f16x8 ld_bfrag(const float* __restrict__ W, int outcol, int ks, int lgrp) {
    const float* p = W + outcol * HDIM + ks * 32 + lgrp * 8;
    float4 a = *(const float4*)p;
    float4 b = *(const float4*)(p + 4);
    f16x8 w = {(_Float16)a.x, (_Float16)a.y, (_Float16)a.z, (_Float16)a.w,
               (_Float16)b.x, (_Float16)b.y, (_Float16)b.z, (_Float16)b.w};
    return w;
}

// ---------------- prep: PT2[v][g] = enc_Wih@emb[v] + enc_bih + (g<512 ? enc_bhh : 0), f16 ----------------
__global__ void pt_kernel(const float* __restrict__ emb, const float* __restrict__ Wih,
                          const float* __restrict__ bih, const float* __restrict__ bhh,
                          _Float16* __restrict__ PT) {
    int v = blockIdx.x;
    __shared__ float se[EDIM];
    for (int e = threadIdx.x; e < EDIM; e += blockDim.x) se[e] = emb[v * EDIM + e];
    __syncthreads();
    for (int g = threadIdx.x; g < G3; g += blockDim.x) {
        const float* wr = Wih + g * EDIM;
        float acc = bih[g] + (g < 512 ? bhh[g] : 0.0f);
        #pragma unroll 8
        for (int e = 0; e < EDIM; ++e) acc += se[e] * wr[e];
        PT[v * G3 + g] = (_Float16)acc;
    }
}

// ===================================================================
// ENCODER: 1024 thr / 16 waves, 16 rows/block. Gates r,z weights in
// registers (64 VGPRs); n-gate weights in LDS (8 KB/wave) -> total
// in-loop reg demand ~108 < 128 cap: NO SPILL by construction.
// ===================================================================
__global__ __launch_bounds__(1024, 4) void enc_kernel(
    const int* __restrict__ x, const _Float16* __restrict__ PT2,
    const float* __restrict__ Whh, const float* __restrict__ bhh,
    float* __restrict__ out)
{
    __shared__ _Float16 s_h[2][16 * H_LD];                         // 16896 B
    __shared__ int s_tok[16 * TT];                                 // 8192 B
    __shared__ __attribute__((aligned(16))) _Float16 s_w2[16 * 4096]; // 131072 B

    const int tid  = threadIdx.x;
    const int lane = tid & 63;
    const int wv   = tid >> 6;
    const int l15  = lane & 15;
    const int lgrp = lane >> 4;
    const int bbase = blockIdx.x * 16;
    const int col  = wv * 16 + l15;

    for (int i = tid; i < 16 * TT; i += 1024) s_tok[i] = x[bbase * TT + i];

    // r,z gates -> registers
    f16x8 Breg[2][8];
    #pragma unroll
    for (int g = 0; g < 2; ++g)
        #pragma unroll
        for (int ks = 0; ks < 8; ++ks)
            Breg[g][ks] = ld_bfrag(Whh, g * 256 + col, ks, lgrp);
    // n gate -> LDS (per-wave region, own fragments only)
    const int w2base = wv * 4096 + lane * 8;     // shorts
    #pragma unroll
    for (int ks = 0; ks < 8; ++ks) {
        f16x8 w = ld_bfrag(Whh, 512 + col, ks, lgrp);
        *(f16x8*)(s_w2 + w2base + ks * 512) = w;
    }

    const float bhn = bhh[512 + col];
    float hst[4] = {0.f, 0.f, 0.f, 0.f};

    for (int i = tid; i < 16 * H_LD; i += 1024) s_h[0][i] = (_Float16)0.f;
    __syncthreads();

    int tokp[4];
    #pragma unroll
    for (int j = 0; j < 4; ++j) tokp[j] = s_tok[(lgrp * 4 + j) * TT];

    const f32x4 z4 = {0.f, 0.f, 0.f, 0.f};

    #pragma unroll 1
    for (int t = 0; t < TT; ++t) {
        const _Float16* rh = s_h[t & 1];
        _Float16* wh = s_h[(t + 1) & 1];

        // issue gate-input gathers FIRST: latency hides under the MFMA phase
        _Float16 pr[4], pz[4], pn[4];
        #pragma unroll
        for (int j = 0; j < 4; ++j) {
            const _Float16* p = PT2 + tokp[j] * G3 + col;
            pr[j] = p[0]; pz[j] = p[256]; pn[j] = p[512];
        }

        f32x4 a0 = z4, a1 = z4, a2 = z4;
        #pragma unroll
        for (int ks = 0; ks < 8; ++ks) {
            f16x8 a  = *(const f16x8*)(rh + l15 * H_LD + ks * 32 + lgrp * 8);
            f16x8 b2 = *(const f16x8*)(s_w2 + w2base + ks * 512);
            a0 = __builtin_amdgcn_mfma_f32_16x16x32_f16(a, Breg[0][ks], a0, 0, 0, 0);
            a1 = __builtin_amdgcn_mfma_f32_16x16x32_f16(a, Breg[1][ks], a1, 0, 0, 0);
            a2 = __builtin_amdgcn_mfma_f32_16x16x32_f16(a, b2,          a2, 0, 0, 0);
        }

        // prefetch next-step tokens (LDS) while gates run
        if (t + 1 < TT) {
            #pragma unroll
            for (int j = 0; j < 4; ++j) tokp[j] = s_tok[(lgrp * 4 + j) * TT + t + 1];
        }

        #pragma unroll
        for (int j = 0; j < 4; ++j) {
            const int row = lgrp * 4 + j;
            float rg = sigf(a0[j] + (float)pr[j]);
            float zg = sigf(a1[j] + (float)pz[j]);
            float n  = tanh_f((float)pn[j] + rg * (a2[j] + bhn));
            float h  = n + zg * (hst[j] - n);
            hst[j] = h;
            wh[row * H_LD + col] = (_Float16)h;
            if (t == TT - 1) out[(size_t)(bbase + row) * LROW + col] = h;
        }
        barrier_lgkm();
    }
}

// ===================================================================
// MID (R13-verified): standalone dec prologue. mu/lv -> out, z -> h0,
// zq = {r+bhr, z+bhz, n, bhn} -> ws.
// ===================================================================
__global__ __launch_bounds__(512, 2) void mid_kernel(
    const float* __restrict__ eps,
    const float* __restrict__ mu_W, const float* __restrict__ mu_b,
    const float* __restrict__ lv_W, const float* __restrict__ lv_b,
    const float* __restrict__ di_W, const float* __restrict__ di_b,
    const float* __restrict__ dec_Wih, const float* __restrict__ dec_bih,
    const float* __restrict__ dec_bhh,
    float* __restrict__ out, f16x4* __restrict__ zq_g, float* __restrict__ h0_g)
{
    __shared__ float s_hl[16 * 260];

    const int tid  = threadIdx.x;
    const int bbase = blockIdx.x * 16;

    for (int i = tid; i < 16 * HDIM; i += 512) {
        int m = i >> 8, c = i & 255;
        s_hl[m * 260 + c] = out[(size_t)(bbase + m) * LROW + c];
    }
    __syncthreads();

    float z0 = 0.f, z1 = 0.f;
    {
        const size_t MU_OFF = (size_t)BB * TT * VOCAB;
        const size_t LV_OFF = MU_OFF + (size_t)BB * LDIM;
        #pragma unroll
        for (int oo = 0; oo < 2; ++oo) {
            int o = tid * 2 + oo;
            int m = o >> 6, j = o & 63;
            const float* mwr = mu_W + j * HDIM;
            const float* lwr = lv_W + j * HDIM;
            float am = mu_b[j], al = lv_b[j];
            #pragma unroll 4
            for (int k = 0; k < HDIM; ++k) { float hv = s_hl[m * 260 + k]; am += hv * mwr[k]; al += hv * lwr[k]; }
            size_t bo = (size_t)(bbase + m) * LDIM + j;
            out[MU_OFF + bo] = am;
            out[LV_OFF + bo] = al;
            float zv = am + eps[bo] * __expf(0.5f * al);
            if (oo == 0) z0 = zv; else z1 = zv;
        }
    }
    __syncthreads();
    {
        int o0 = tid * 2;
        s_hl[(o0 >> 6) * 260 + (o0 & 63)] = z0;
        int o1 = o0 + 1;
        s_hl[(o1 >> 6) * 260 + (o1 & 63)] = z1;
    }
    __syncthreads();

    {
        const int gc = tid & 255;
        const int gm2 = tid >> 8;
        float ah[8], ar[8], az[8], an[8];
        float dib = di_b[gc];
        float bir = dec_bih[gc], biz = dec_bih[gc + 256], bin_ = dec_bih[gc + 512];
        #pragma unroll
        for (int i = 0; i < 8; ++i) { ah[i] = dib; ar[i] = bir; az[i] = biz; an[i] = bin_; }
        const float* w0 = di_W + gc * LDIM;
        const float* w1 = dec_Wih + gc * LDIM;
        const float* w2 = dec_Wih + (gc + 256) * LDIM;
        const float* w3 = dec_Wih + (gc + 512) * LDIM;
        #pragma unroll 2
        for (int j = 0; j < LDIM; ++j) {
            float a0 = w0[j], a1 = w1[j], a2 = w2[j], a3 = w3[j];
            #pragma unroll
            for (int i = 0; i < 8; ++i) {
                float q = s_hl[(gm2 + 2 * i) * 260 + j];
                ah[i] += q * a0; ar[i] += q * a1; az[i] += q * a2; an[i] += q * a3;
            }
        }
        float bhr = dec_bhh[gc], bhz = dec_bhh[gc + 256], bhn_c = dec_bhh[gc + 512];
        #pragma unroll
        for (int i = 0; i < 8; ++i) {
            int m = gm2 + 2 * i;
            float th = tanh_f(ah[i]);
            h0_g[(size_t)(bbase + m) * 256 + gc] = th;
            f16x4 q = {(_Float16)(ar[i] + bhr), (_Float16)(az[i] + bhz), (_Float16)an[i], (_Float16)bhn_c};
            zq_g[(size_t)(bbase + m) * 256 + gc] = q;
        }
    }
}

// ===================================================================
// DECODER RNN (R13-verified): 1024 thr / 16 waves, pure GRU loop.
// ===================================================================
__global__ __launch_bounds__(1024, 4) void dec_rnn_kernel(
    const float* __restrict__ dec_Whh,
    const f16x4* __restrict__ zq_g, const float* __restrict__ h0_g,
    _Float16* __restrict__ Hbuf)
{
    __shared__ _Float16 s_hb[2][16 * H_LD];   // 16896 B
    __shared__ f16x4 s_zq[256 * ZP_LD];       // 34816 B

    const int tid  = threadIdx.x;
    const int lane = tid & 63;
    const int wv   = tid >> 6;
    const int l15  = lane & 15;
    const int lgrp = lane >> 4;
    const int bbase = blockIdx.x * 16;
    const int col  = wv * 16 + l15;

    for (int i = tid; i < 16 * HDIM; i += 1024) {
        int row = i >> 8, c = i & 255;
        float hv = h0_g[(size_t)(bbase + row) * 256 + c];
        s_hb[0][row * H_LD + c] = (_Float16)hv;
        s_zq[c * ZP_LD + row] = zq_g[(size_t)(bbase + row) * 256 + c];
    }

    f16x8 Breg[3][8];
    #pragma unroll
    for (int g = 0; g < 3; ++g)
        #pragma unroll
        for (int ks = 0; ks < 8; ++ks)
            Breg[g][ks] = ld_bfrag(dec_Whh, g * 256 + col, ks, lgrp);

    float hst[4];
    #pragma unroll
    for (int j = 0; j < 4; ++j)
        hst[j] = h0_g[(size_t)(bbase + lgrp * 4 + j) * 256 + col];
    __syncthreads();

    const f32x4 z4 = {0.f, 0.f, 0.f, 0.f};
    const int crow = tid >> 6;       // 0..15
    const int cseg = lane;           // 0..63 (8B chunks)
    _Float16* hb = Hbuf + ((size_t)(bbase + crow) * TT) * 256 + cseg * 4;
    const int lread = crow * H_LD + cseg * 4;

    #pragma unroll 1
    for (int t = 0; t < TT; ++t) {
        const _Float16* rh = s_hb[t & 1];
        _Float16* wh = s_hb[(t + 1) & 1];

        f32x4 a0 = z4, a1 = z4, a2 = z4;
        #pragma unroll
        for (int ks = 0; ks < 8; ++ks) {
            f16x8 a = *(const f16x8*)(rh + l15 * H_LD + ks * 32 + lgrp * 8);
            a0 = __builtin_amdgcn_mfma_f32_16x16x32_f16(a, Breg[0][ks], a0, 0, 0, 0);
            a1 = __builtin_amdgcn_mfma_f32_16x16x32_f16(a, Breg[1][ks], a1, 0, 0, 0);
            a2 = __builtin_amdgcn_mfma_f32_16x16x32_f16(a, Breg[2][ks], a2, 0, 0, 0);
        }
        #pragma unroll
        for (int j = 0; j < 4; ++j) {
            const int row = lgrp * 4 + j;
            f16x4 q = s_zq[col * ZP_LD + row];
            float rg = sigf(a0[j] + (float)q[0]);
            float zg = sigf(a1[j] + (float)q[1]);
            float n  = tanh_f((float)q[2] + rg * (a2[j] + (float)q[3]));
            float h  = n + zg * (hst[j] - n);
            hst[j] = h;
            wh[row * H_LD + col] = (_Float16)h;
        }
        barrier_lgkm();
        *(f16x4*)hb = *(const f16x4*)(wh + lread);
        hb += 256;
    }
}

// ===================================================================
// LOGITS GEMM (R10/R13-verified): LDS-staged LINEAR copy-out.
// ===================================================================
__global__ __launch_bounds__(1024, 4) void logits_kernel(
    const _Float16* __restrict__ Hbuf, const float* __restrict__ out_W,
    const float* __restrict__ out_b, float* __restrict__ out)
{
    __shared__ __attribute__((aligned(16))) unsigned char s_outw[VOCAB * 512]; // 51200 B
    __shared__ __attribute__((aligned(16))) float s_ls[256 * 108];             // 110592 B
    const int tid = threadIdx.x, lane = tid & 63, wv = tid >> 6;
    const int l15 = lane & 15, lgrp = lane >> 4;

    for (int idx = tid; idx < VOCAB * HDIM; idx += 1024) {
        int r = idx >> 8, k = idx & 255;
        _Float16 w = (_Float16)out_W[r * 256 + k];
        *(short*)(s_outw + r * 512 + ((2 * k) ^ ((r & 7) << 4))) = __builtin_bit_cast(short, w);
    }
    __syncthreads();

    float ob[7];
    #pragma unroll
    for (int vt = 0; vt < 7; ++vt) {
        int v = vt * 16 + l15;
        ob[vt] = (v < VOCAB) ? out_b[v] : 0.0f;
    }
    const f32x4 z4 = {0.f, 0.f, 0.f, 0.f};

    #pragma unroll 1
    for (int round = 0; round < 2; ++round) {
        size_t mt = (size_t)blockIdx.x * 32 + round * 16 + wv;
        const _Float16* hrow = Hbuf + (mt * 16 + l15) * 256;
        f32x4 acc[7];
        #pragma unroll
        for (int vt = 0; vt < 7; ++vt) acc[vt] = z4;
        #pragma unroll
        for (int ks = 0; ks < 8; ++ks) {
            f16x8 a = *(const f16x8*)(hrow + ks * 32 + lgrp * 8);
            #pragma unroll
            for (int vt = 0; vt < 7; ++vt) {
                int orow = vt * 16 + l15; if (orow > VOCAB - 1) orow = VOCAB - 1;
                f16x8 wo = *(const f16x8*)(s_outw + orow * 512 + ((ks * 64 + lgrp * 16) ^ ((orow & 7) << 4)));
                acc[vt] = __builtin_amdgcn_mfma_f32_16x16x32_f16(a, wo, acc[vt], 0, 0, 0);
            }
        }
        #pragma unroll
        for (int vt = 0; vt < 7; ++vt) {
            int v = vt * 16 + l15;
            if (v < VOCAB) {
                #pragma unroll
                for (int j = 0; j < 4; ++j)
                    s_ls[(wv * 16 + lgrp * 4 + j) * 108 + v] = acc[vt][j] + ob[vt];
            }
        }
        __syncthreads();
        {
            size_t slabM0 = (size_t)blockIdx.x * 512 + round * 256;
            float* gbase = out + slabM0 * VOCAB;
            for (int c = tid; c < 6400; c += 1024) {
                int r = c / 25, cc = (c % 25) * 4;
                f32x4 vch = *(const f32x4*)(s_ls + r * 108 + cc);
                *(f32x4*)(gbase + (size_t)c * 4) = vch;
            }
        }
        __syncthreads();
    }
}

// ===================================================================
// FALLBACK fused decoder (known-passing) — used if ws too small.
// ===================================================================
__global__ __launch_bounds__(1024, 4) void dec_fused_kernel(
    const float* __restrict__ eps,
    const float* __restrict__ mu_W, const float* __restrict__ mu_b,
    const float* __restrict__ lv_W, const float* __restrict__ lv_b,
    const float* __restrict__ di_W, const float* __restrict__ di_b,
    const float* __restrict__ dec_Wih, const float* __restrict__ dec_Whh,
    const float* __restrict__ dec_bih, const float* __restrict__ dec_bhh,
    const float* __restrict__ out_W, const float* __restrict__ out_b,
    float* __restrict__ out)
{
    __shared__ _Float16 s_hb[2][16 * H_LD];
    __shared__ f16x4 s_zp[256 * ZP_LD];
    __shared__ __attribute__((aligned(16))) unsigned char s_outw[VOCAB * 512];
    __shared__ float s_hl[16 * 260];

    const int tid  = threadIdx.x;
    const int lane = tid & 63;
    const int wv   = tid >> 6;
    const int l15  = lane & 15;
    const int lgrp = lane >> 4;
    const int bbase = blockIdx.x * 16;
    const int col  = wv * 16 + l15;

    for (int i = tid; i < 16 * HDIM; i += 1024) {
        int m = i >> 8, c = i & 255;
        s_hl[m * 260 + c] = out[(size_t)(bbase + m) * LROW + c];
    }
    for (int idx = tid; idx < VOCAB * HDIM; idx += 1024) {
        int r = idx >> 8, k = idx & 255;
        _Float16 w = (_Float16)out_W[r * 256 + k];
        *(short*)(s_outw + r * 512 + ((2 * k) ^ ((r & 7) << 4))) = __builtin_bit_cast(short, w);
    }

    f16x8 Breg[3][8];
    #pragma unroll
    for (int g = 0; g < 3; ++g)
        #pragma unroll
        for (int ks = 0; ks < 8; ++ks)
            Breg[g][ks] = ld_bfrag(dec_Whh, g * 256 + col, ks, lgrp);
    __syncthreads();

    float zv;
    {
        const size_t MU_OFF = (size_t)BB * TT * VOCAB;
        const size_t LV_OFF = MU_OFF + (size_t)BB * LDIM;
        int m = tid >> 6, j = tid & 63;
        const float* mwr = mu_W + j * HDIM;
        const float* lwr = lv_W + j * HDIM;
        float am = mu_b[j], al = lv_b[j];
        #pragma unroll 4
        for (int k = 0; k < HDIM; ++k) { float hv = s_hl[m * 260 + k]; am += hv * mwr[k]; al += hv * lwr[k]; }
        size_t bo = (size_t)(bbase + m) * LDIM + j;
        out[MU_OFF + bo] = am;
        out[LV_OFF + bo] = al;
        zv = am + eps[bo] * __expf(0.5f * al);
    }
    __syncthreads();
    { int m = tid >> 6, j = tid & 63; s_hl[m * 260 + j] = zv; }
    __syncthreads();

    float th[4];
    {
        const int gc = tid & 255;
        const int gm = tid >> 8;
        float ah[4], ar[4], az[4], an[4];
        float dib = di_b[gc];
        float bir = dec_bih[gc], biz = dec_bih[gc + 256], bin_ = dec_bih[gc + 512];
        #pragma unroll
        for (int i = 0; i < 4; ++i) { ah[i] = dib; ar[i] = bir; az[i] = biz; an[i] = bin_; }
        const float* w0 = di_W + gc * LDIM;
        const float* w1 = dec_Wih + gc * LDIM;
        const float* w2 = dec_Wih + (gc + 256) * LDIM;
        const float* w3 = dec_Wih + (gc + 512) * LDIM;
        #pragma unroll 2
        for (int j = 0; j < LDIM; ++j) {
            float a0 = w0[j], a1 = w1[j], a2 = w2[j], a3 = w3[j];
            #pragma unroll
            for (int i = 0; i < 4; ++i) {
                float q = s_hl[(gm * 4 + i) * 260 + j];
                ah[i] += q * a0; ar[i] += q * a1; az[i] += q * a2; an[i] += q * a3;
            }
        }
        float bhr = dec_bhh[gc], bhz = dec_bhh[gc + 256];
        __syncthreads();
        #pragma unroll
        for (int i = 0; i < 4; ++i) {
            int r = gm * 4 + i;
            th[i] = tanh_f(ah[i]);
            s_hl[r * 260 + gc] = th[i];
            f16x4 q = {(_Float16)(ar[i] + bhr), (_Float16)(az[i] + bhz), (_Float16)an[i], (_Float16)0.f};
            s_zp[gc * ZP_LD + r] = q;
            s_hb[0][r * H_LD + gc] = (_Float16)th[i];
        }
    }
    __syncthreads();

    float hpr[4];
    #pragma unroll
    for (int j = 0; j < 4; ++j) hpr[j] = s_hl[(lgrp * 4 + j) * 260 + col];

    const float bhn = dec_bhh[512 + col];
    const int vcol = wv * 16 + l15;
    const int orow = (vcol < VOCAB) ? vcol : (VOCAB - 1);
    const float ob = (wv < 7 && vcol < VOCAB) ? out_b[vcol] : 0.0f;
    const f32x4 z4 = {0.f, 0.f, 0.f, 0.f};

    #pragma unroll 1
    for (int t = 0; t < TT; ++t) {
        const _Float16* rh = s_hb[t & 1];
        _Float16* wh = s_hb[(t + 1) & 1];

        f32x4 a0 = z4, a1 = z4, a2 = z4, aco = z4;
        #pragma unroll
        for (int ks = 0; ks < 8; ++ks) {
            f16x8 a = *(const f16x8*)(rh + l15 * H_LD + ks * 32 + lgrp * 8);
            a0 = __builtin_amdgcn_mfma_f32_16x16x32_f16(a, Breg[0][ks], a0, 0, 0, 0);
            a1 = __builtin_amdgcn_mfma_f32_16x16x32_f16(a, Breg[1][ks], a1, 0, 0, 0);
            a2 = __builtin_amdgcn_mfma_f32_16x16x32_f16(a, Breg[2][ks], a2, 0, 0, 0);
            if (wv < 7) {
                f16x8 wo = *(const f16x8*)(s_outw + orow * 512 + ((ks * 64 + lgrp * 16) ^ ((orow & 7) << 4)));
                aco = __builtin_amdgcn_mfma_f32_16x16x32_f16(a, wo, aco, 0, 0, 0);
            }
        }
        if (t > 0 && wv < 7 && vcol < VOCAB) {
            size_t base = (size_t)(bbase + lgrp * 4) * LROW + (size_t)(t - 1) * VOCAB + vcol;
            #pragma unroll
            for (int j = 0; j < 4; ++j) out[base + (size_t)j * LROW] = aco[j] + ob;
        }
        #pragma unroll
        for (int j = 0; j < 4; ++j) {
            const int row = lgrp * 4 + j;
            f16x4 q = s_zp[col * ZP_LD + lgrp * 4 + j];
            float rg = sigf(a0[j] + (float)q[0]);
            float zg = sigf(a1[j] + (float)q[1]);
            float n  = tanh_f((float)q[2] + rg * (a2[j] + bhn));
            float h  = n + zg * (hpr[j] - n);
            hpr[j] = h;
            wh[row * H_LD + col] = (_Float16)h;
        }
        barrier_lgkm();
    }

    if (wv < 7) {
        const _Float16* rh = s_hb[0];
        f32x4 aco = z4;
        #pragma unroll
        for (int ks = 0; ks < 8; ++ks) {
            f16x8 a  = *(const f16x8*)(rh + l15 * H_LD + ks * 32 + lgrp * 8);
            f16x8 wo = *(const f16x8*)(s_outw + orow * 512 + ((ks * 64 + lgrp * 16) ^ ((orow & 7) << 4)));
            aco = __builtin_amdgcn_mfma_f32_16x16x32_f16(a, wo, aco, 0, 0, 0);
        }
        if (vcol < VOCAB) {
            size_t base = (size_t)(bbase + lgrp * 4) * LROW + (size_t)(TT - 1) * VOCAB + vcol;
            #pragma unroll
            for (int j = 0; j < 4; ++j) out[base + (size_t)j * LROW] = aco[j] + ob;
        }
    }
}

extern "C" void kernel_launch(void* const* d_in, const int* in_sizes, int n_in,
                              void* d_out, int out_size, void* d_ws, size_t ws_size,
                              hipStream_t stream) {
    const int*   x       = (const int*)  d_in[0];
    const float* eps     = (const float*)d_in[1];
    const float* emb     = (const float*)d_in[2];
    const float* enc_Wih = (const float*)d_in[3];
    const float* enc_Whh = (const float*)d_in[4];
    const float* enc_bih = (const float*)d_in[5];
    const float* enc_bhh = (const float*)d_in[6];
    const float* mu_W    = (const float*)d_in[7];
    const float* mu_b    = (const float*)d_in[8];
    const float* lv_W    = (const float*)d_in[9];
    const float* lv_b    = (const float*)d_in[10];
    const float* di_W    = (const float*)d_in[11];
    const float* di_b    = (const float*)d_in[12];
    const float* dec_Wih = (const float*)d_in[13];
    const float* dec_Whh = (const float*)d_in[14];
    const float* dec_bih = (const float*)d_in[15];
    const float* dec_bhh = (const float*)d_in[16];
    const float* out_W   = (const float*)d_in[17];
    const float* out_b   = (const float*)d_in[18];
    float* out = (float*)d_out;

    // ws layout: PT | zq | h0 | Hbuf
    _Float16* PT = (_Float16*)d_ws;                                  // 153600 B
    const size_t ZQ_OFF = 153600;
    const size_t H0_OFF = ZQ_OFF + (size_t)BB * 256 * 8;             // zq: 8 MB
    const size_t HB_OFF = H0_OFF + (size_t)BB * 256 * 4;             // h0: 4 MB
    f16x4*    zq_g = (f16x4*)((char*)d_ws + ZQ_OFF);
    float*    h0_g = (float*)((char*)d_ws + H0_OFF);
    _Float16* Hbuf = (_Float16*)((char*)d_ws + HB_OFF);              // 268.4 MB
    const size_t need = HB_OFF + (size_t)BB * TT * 256 * sizeof(_Float16);

    pt_kernel<<<VOCAB, 256, 0, stream>>>(emb, enc_Wih, enc_bih, enc_bhh, PT);
    enc_kernel<<<BB / 16, 1024, 0, stream>>>(x, PT, enc_Whh, enc_bhh, out);
    if (ws_size >= need) {
        mid_kernel<<<BB / 16, 512, 0, stream>>>(eps, mu_W, mu_b, lv_W, lv_b,
            di_W, di_b, dec_Wih, dec_bih, dec_bhh, out, zq_g, h0_g);
        dec_rnn_kernel<<<BB / 16, 1024, 0, stream>>>(dec_Whh, zq_g, h0_g, Hbuf);
        logits_kernel<<<(BB * TT / 16) / 32, 1024, 0, stream>>>(Hbuf, out_W, out_b, out);
    } else {
        dec_fused_kernel<<<BB / 16, 1024, 0, stream>>>(eps, mu_W, mu_b, lv_W, lv_b,
            di_W, di_b, dec_Wih, dec_Whh, dec_bih, dec_bhh, out_W, out_b, out);
    }
}